// Round 3
// 1319.755 us; speedup vs baseline: 1.5150x; 1.5150x over previous
//
#include <hip/hip_runtime.h>
#include <hip/hip_bf16.h>
#include <math.h>

#define S 2048
#define NH 4
#define FD 512
#define CHUNK 1024
#define BASE_LR_INV -6.9072552373f

typedef unsigned short u16;
typedef unsigned int u32;
typedef short bhalf8 __attribute__((ext_vector_type(8)));   // 8 bf16 = 4 VGPRs
typedef float floatx4 __attribute__((ext_vector_type(4)));

__device__ __forceinline__ u16 f2bf(float f) {               // RNE fp32->bf16
    u32 x = __float_as_uint(f);
    return (u16)((x + 0x7FFFu + ((x >> 16) & 1u)) >> 16);
}
__device__ __forceinline__ float bf2f(u16 u) {
    return __uint_as_float(((u32)u) << 16);
}
__device__ __forceinline__ float ldval(const float* p) { return *p; }
__device__ __forceinline__ float ldval(const u16* p) { return bf2f(*p); }

// ---------------------------------------------------------------------------
// bf16 MFMA GEMM:  C(fp32) = A @ B^T, A:(M,K) bf16 lda, B:(N,K) bf16 ldb.
// 128x128 block tile, 256 thr = 4 waves (2x2 of 64x64), BK=32,
// v_mfma_f32_16x16x32_bf16. acc_flag: C += result.
// Batched: ptr += (z>>2)*offO + (z&3)*offI.
// M,N mult of 128; K mult of 32.
// ---------------------------------------------------------------------------
__global__ __launch_bounds__(256) void gemm_mfma(
    const u16* __restrict__ A, int lda, long offAo, long offAi,
    const u16* __restrict__ B, int ldb, long offBo, long offBi,
    float* __restrict__ C, int ldc, long offCo, long offCi, int K, int acc_flag)
{
    int z = blockIdx.z;
    A += (long)(z >> 2) * offAo + (long)(z & 3) * offAi;
    B += (long)(z >> 2) * offBo + (long)(z & 3) * offBi;
    C += (long)(z >> 2) * offCo + (long)(z & 3) * offCi;
    __shared__ u16 As[128][40];   // +8 pad: rows 80 B apart (16B-aligned)
    __shared__ u16 Bs[128][40];
    const int tid = threadIdx.x;
    const int wid = tid >> 6, lane = tid & 63;
    const int quad = lane >> 4, l15 = lane & 15;
    const int m0w = (wid >> 1) * 64, n0w = (wid & 1) * 64;
    const int row0 = blockIdx.y * 128, col0 = blockIdx.x * 128;
    const int srow = tid >> 1, scol = (tid & 1) * 16;   // staging map: 16 bf16/thread

    floatx4 acc[4][4];
#pragma unroll
    for (int a = 0; a < 4; ++a)
#pragma unroll
        for (int b = 0; b < 4; ++b) acc[a][b] = {0.f, 0.f, 0.f, 0.f};

    for (int kk = 0; kk < K; kk += 32) {
        const u16* ga = &A[(long)(row0 + srow) * lda + kk + scol];
        const u16* gb = &B[(long)(col0 + srow) * ldb + kk + scol];
        *reinterpret_cast<uint4*>(&As[srow][scol])     = *reinterpret_cast<const uint4*>(ga);
        *reinterpret_cast<uint4*>(&As[srow][scol + 8]) = *reinterpret_cast<const uint4*>(ga + 8);
        *reinterpret_cast<uint4*>(&Bs[srow][scol])     = *reinterpret_cast<const uint4*>(gb);
        *reinterpret_cast<uint4*>(&Bs[srow][scol + 8]) = *reinterpret_cast<const uint4*>(gb + 8);
        __syncthreads();
        bhalf8 af[4], bf[4];
#pragma unroll
        for (int mt = 0; mt < 4; ++mt)
            af[mt] = *reinterpret_cast<const bhalf8*>(&As[m0w + mt * 16 + l15][quad * 8]);
#pragma unroll
        for (int nt = 0; nt < 4; ++nt)
            bf[nt] = *reinterpret_cast<const bhalf8*>(&Bs[n0w + nt * 16 + l15][quad * 8]);
#pragma unroll
        for (int mt = 0; mt < 4; ++mt)
#pragma unroll
            for (int nt = 0; nt < 4; ++nt)
                acc[mt][nt] = __builtin_amdgcn_mfma_f32_16x16x32_bf16(
                    af[mt], bf[nt], acc[mt][nt], 0, 0, 0);
        __syncthreads();
    }
#pragma unroll
    for (int mt = 0; mt < 4; ++mt)
#pragma unroll
        for (int nt = 0; nt < 4; ++nt) {
            int col = col0 + n0w + nt * 16 + l15;
#pragma unroll
            for (int r = 0; r < 4; ++r) {
                int row = row0 + m0w + mt * 16 + quad * 4 + r;
                long off = (long)row * ldc + col;
                float v = acc[mt][nt][r];
                C[off] = acc_flag ? (C[off] + v) : v;
            }
        }
}

// ---------------------------------------------------------------------------
// flat fp32 -> bf16 convert (n mult of 4)
// ---------------------------------------------------------------------------
__global__ __launch_bounds__(256) void cvt_bf16(
    const float* __restrict__ in, u16* __restrict__ out, long n)
{
    long i = ((long)blockIdx.x * 256 + threadIdx.x) * 4;
    if (i >= n) return;
    float4 v = *reinterpret_cast<const float4*>(&in[i]);
    ushort4 o;
    o.x = f2bf(v.x); o.y = f2bf(v.y); o.z = f2bf(v.z); o.w = f2bf(v.w);
    *reinterpret_cast<ushort4*>(&out[i]) = o;
}

// ---------------------------------------------------------------------------
// batched transpose + cvt: in[z] (R,C) ld=ldin  ->  out[z] (C,R) bf16 ld=ldout
// grid (C/64, R/64, 8)
// ---------------------------------------------------------------------------
template <typename TIN>
__global__ __launch_bounds__(256) void transpose_cvt(
    const TIN* __restrict__ in, int ldin, long inOo, long inOi,
    u16* __restrict__ out, int ldout, long outOo, long outOi)
{
    int z = blockIdx.z;
    in  += (long)(z >> 2) * inOo + (long)(z & 3) * inOi;
    out += (long)(z >> 2) * outOo + (long)(z & 3) * outOi;
    int r0 = blockIdx.y * 64, c0 = blockIdx.x * 64;
    __shared__ float t[64][65];
    for (int i = threadIdx.x; i < 4096; i += 256) {
        int r = i >> 6, c = i & 63;
        t[r][c] = ldval(&in[(long)(r0 + r) * ldin + c0 + c]);
    }
    __syncthreads();
    for (int i = threadIdx.x; i < 4096; i += 256) {
        int r = i >> 6, c = i & 63;
        out[(long)(c0 + r) * ldout + r0 + c] = f2bf(t[c][r]);
    }
}

// ---------------------------------------------------------------------------
// V transpose for attention: qkv V slice (b,s,h,128) fp32 -> vt (b,h,128,s) bf16
// grid (S/64, 128/64, b*16)
// ---------------------------------------------------------------------------
__global__ __launch_bounds__(256) void vt_prep(
    const float* __restrict__ qkv, u16* __restrict__ vt)
{
    int z = blockIdx.z;          // b*16 + h
    int b_ = z >> 4, h = z & 15;
    int s0 = blockIdx.x * 64, d0 = blockIdx.y * 64;
    __shared__ float t[64][65];
    const float* src = &qkv[(long)(b_ * S) * 6144 + 4096 + h * 128 + d0];
    for (int i = threadIdx.x; i < 4096; i += 256) {
        int r = i >> 6, c = i & 63;      // r: s, c: d
        t[r][c] = src[(long)(s0 + r) * 6144 + c];
    }
    __syncthreads();
    u16* dst = &vt[((long)z * 128 + d0) * 2048 + s0];
    for (int i = threadIdx.x; i < 4096; i += 256) {
        int r = i >> 6, c = i & 63;      // r: d, c: s
        dst[(long)r * 2048 + c] = f2bf(t[c][r]);
    }
}

// ---------------------------------------------------------------------------
// lr = softplus(hs @ lr_w^T + lr_b + BASE_LR_INV)  -> (4096, 12)
// ---------------------------------------------------------------------------
__global__ __launch_bounds__(256) void lr_kernel(
    const float* __restrict__ hs, const float* __restrict__ lr_w,
    const float* __restrict__ lr_b, float* __restrict__ lr)
{
    int row = blockIdx.x;
    __shared__ float hrow[2048];
    __shared__ float red[256];
    for (int i = threadIdx.x; i < 2048; i += 256) hrow[i] = hs[(long)row * 2048 + i];
    __syncthreads();
    for (int j = 0; j < 12; ++j) {
        float ss = 0.f;
        for (int i = threadIdx.x; i < 2048; i += 256) ss += hrow[i] * lr_w[(long)j * 2048 + i];
        red[threadIdx.x] = ss; __syncthreads();
        for (int s_ = 128; s_ > 0; s_ >>= 1) {
            if (threadIdx.x < s_) red[threadIdx.x] += red[threadIdx.x + s_];
            __syncthreads();
        }
        if (threadIdx.x == 0) {
            float x = red[0] + lr_b[j] + BASE_LR_INV;
            lr[(long)row * 12 + j] = (x > 20.f) ? x : log1pf(expf(x));
        }
        __syncthreads();
    }
}

// ---------------------------------------------------------------------------
// rmsnorm over d=2048 + RoPE per head (hd=128) -> packed bf16 (b,s,16,128)
// ---------------------------------------------------------------------------
__global__ __launch_bounds__(256) void rmsnorm_rope(
    const float* __restrict__ qkv, int colOff, const float* __restrict__ w,
    u16* __restrict__ out)
{
    int row = blockIdx.x;            // b*s
    int si = row & (S - 1);
    const float* x = &qkv[(long)row * 6144 + colOff];
    __shared__ float xn[2048];
    __shared__ float red[256];
    float ss = 0.f;
    for (int i = threadIdx.x; i < 2048; i += 256) { float v = x[i]; ss += v * v; }
    red[threadIdx.x] = ss; __syncthreads();
    for (int s_ = 128; s_ > 0; s_ >>= 1) {
        if (threadIdx.x < s_) red[threadIdx.x] += red[threadIdx.x + s_];
        __syncthreads();
    }
    float scale = rsqrtf(red[0] / 2048.f + 1e-6f);
    for (int i = threadIdx.x; i < 2048; i += 256) xn[i] = x[i] * scale * w[i];
    __syncthreads();
    for (int i = threadIdx.x; i < 2048; i += 256) {
        int tt = i & 127;
        int t2 = tt & 63;
        float inv_freq = powf(500000.0f, -(float)t2 / 64.0f);
        float ang = (float)si * inv_freq;
        float sn, cs;
        sincosf(ang, &sn, &cs);
        float v;
        if (tt < 64) v = xn[i] * cs - xn[i + 64] * sn;
        else         v = xn[i] * cs + xn[i - 64] * sn;
        out[(long)row * 2048 + i] = f2bf(v);
    }
}

// ---------------------------------------------------------------------------
// Flash-style sliding-window causal attention, bf16 MFMA.
// Block: 64 q-rows x one head; 256 thr = 4 waves.
// QK^T: waves 2x2 over (32q x 32kv). PV: waves 2x2 over (32q x 64d).
// aq/ak: bf16 (b*s, 2048) with head at h*128. vt: bf16 (b,h,128,2048).
// ---------------------------------------------------------------------------
__global__ __launch_bounds__(256) void attn_mfma(
    const u16* __restrict__ aq, const u16* __restrict__ ak,
    const u16* __restrict__ vt, float* __restrict__ attn_out)
{
    const int qt = blockIdx.x;   // 0..31
    const int h  = blockIdx.y;   // 0..15
    const int b_ = blockIdx.z;   // 0..1
    const int q0 = qt * 64;
    const int tid = threadIdx.x;
    const int wid = tid >> 6, lane = tid & 63;
    const int quad = lane >> 4, l15 = lane & 15;
    const int m0w = (wid >> 1) * 32;      // q rows for this wave
    const int n0w = (wid & 1) * 32;       // kv cols (QK phase)
    const int n0v = (wid & 1) * 64;       // d cols (PV phase)
    const float scale = 0.088388347648318447f;

    __shared__ u16  Ks[64][136];   // K tile (also Q staging); 272B rows, 16B aligned
    __shared__ float Ss[64][67];   // scores; pad 67 -> conflict-free softmax reads
    __shared__ u16  Ps[64][72];    // P bf16; 144B rows
    __shared__ u16  Vs[128][72];   // V^T tile: [d][kv]
    __shared__ float alphas[64];
    __shared__ float lsum[64];

    const long qkbase = (long)(b_ * S + q0) * 2048 + h * 128;
    const long vtbase = ((long)(b_ * 16 + h)) * 128 * 2048;

    // ---- stage Q tile into Ks, hoist Q fragments into registers ----
    {
        int r = tid >> 2, c = (tid & 3) * 32;
        const u16* g = &aq[qkbase + (long)r * 2048 + c];
#pragma unroll
        for (int o = 0; o < 32; o += 8)
            *reinterpret_cast<uint4*>(&Ks[r][c + o]) = *reinterpret_cast<const uint4*>(g + o);
    }
    __syncthreads();
    bhalf8 qf[2][4];
#pragma unroll
    for (int mt = 0; mt < 2; ++mt)
#pragma unroll
        for (int ks = 0; ks < 4; ++ks)
            qf[mt][ks] = *reinterpret_cast<const bhalf8*>(&Ks[m0w + mt * 16 + l15][ks * 32 + quad * 8]);
    __syncthreads();

    floatx4 oacc[2][4];
#pragma unroll
    for (int mt = 0; mt < 2; ++mt)
#pragma unroll
        for (int nt = 0; nt < 4; ++nt) oacc[mt][nt] = {0.f, 0.f, 0.f, 0.f};
    float m_i = -3.4e38f, l_i = 0.f;           // row = tid>>2 (4 threads replicate)
    const int srow_sm = tid >> 2, scol_sm = (tid & 3) * 16;

    const int st = (qt >= 16) ? (qt - 16) : 0;
    for (int kt = st; kt <= qt; ++kt) {
        const int j0 = kt * 64;
        // stage K tile (64 x 128 bf16)
        {
            int r = tid >> 2, c = (tid & 3) * 32;
            const u16* g = &ak[(long)(b_ * S + j0) * 2048 + h * 128 + (long)r * 2048 + c];
#pragma unroll
            for (int o = 0; o < 32; o += 8)
                *reinterpret_cast<uint4*>(&Ks[r][c + o]) = *reinterpret_cast<const uint4*>(g + o);
        }
        // stage V^T tile (128 d-rows x 64 kv-cols bf16)
        {
            int r = tid >> 1, c = (tid & 1) * 32;
            const u16* g = &vt[vtbase + (long)r * 2048 + j0 + c];
#pragma unroll
            for (int o = 0; o < 32; o += 8)
                *reinterpret_cast<uint4*>(&Vs[r][c + o]) = *reinterpret_cast<const uint4*>(g + o);
        }
        __syncthreads();

        // ---- QK^T: 32x32 quadrant per wave ----
        floatx4 sacc[2][2];
#pragma unroll
        for (int mt = 0; mt < 2; ++mt)
#pragma unroll
            for (int nt = 0; nt < 2; ++nt) sacc[mt][nt] = {0.f, 0.f, 0.f, 0.f};
#pragma unroll
        for (int ks = 0; ks < 4; ++ks) {
            bhalf8 kf0 = *reinterpret_cast<const bhalf8*>(&Ks[n0w + l15][ks * 32 + quad * 8]);
            bhalf8 kf1 = *reinterpret_cast<const bhalf8*>(&Ks[n0w + 16 + l15][ks * 32 + quad * 8]);
            sacc[0][0] = __builtin_amdgcn_mfma_f32_16x16x32_bf16(qf[0][ks], kf0, sacc[0][0], 0, 0, 0);
            sacc[0][1] = __builtin_amdgcn_mfma_f32_16x16x32_bf16(qf[0][ks], kf1, sacc[0][1], 0, 0, 0);
            sacc[1][0] = __builtin_amdgcn_mfma_f32_16x16x32_bf16(qf[1][ks], kf0, sacc[1][0], 0, 0, 0);
            sacc[1][1] = __builtin_amdgcn_mfma_f32_16x16x32_bf16(qf[1][ks], kf1, sacc[1][1], 0, 0, 0);
        }
        // masked + scaled scores to LDS
#pragma unroll
        for (int mt = 0; mt < 2; ++mt)
#pragma unroll
            for (int nt = 0; nt < 2; ++nt)
#pragma unroll
                for (int r = 0; r < 4; ++r) {
                    int row = m0w + mt * 16 + quad * 4 + r;
                    int col = n0w + nt * 16 + l15;
                    int i_abs = q0 + row, j_abs = j0 + col;
                    bool valid = (j_abs <= i_abs) && (i_abs - j_abs < 1024);
                    Ss[row][col] = valid ? sacc[mt][nt][r] * scale : -3.4e38f;
                }
        __syncthreads();

        // ---- online softmax: 4 consecutive lanes per row ----
        {
            float sv[16];
            float mx = -3.4e38f;
#pragma unroll
            for (int j = 0; j < 16; ++j) {
                sv[j] = Ss[srow_sm][scol_sm + j];
                mx = fmaxf(mx, sv[j]);
            }
            mx = fmaxf(mx, __shfl_xor(mx, 1));
            mx = fmaxf(mx, __shfl_xor(mx, 2));
            float m_new = fmaxf(m_i, mx);
            float alpha = expf(m_i - m_new);     // -3.4e38 - finite -> 0; 0 when stale
            float psum = 0.f;
#pragma unroll
            for (int j = 0; j < 16; ++j) {
                float p = (sv[j] > -1e30f) ? expf(sv[j] - m_new) : 0.f;
                Ps[srow_sm][scol_sm + j] = f2bf(p);
                psum += p;
            }
            psum += __shfl_xor(psum, 1);
            psum += __shfl_xor(psum, 2);
            l_i = l_i * alpha + psum;
            m_i = m_new;
            if ((tid & 3) == 0) alphas[srow_sm] = alpha;
        }
        __syncthreads();

        // ---- rescale O, then PV MFMA ----
#pragma unroll
        for (int mt = 0; mt < 2; ++mt)
#pragma unroll
            for (int r = 0; r < 4; ++r) {
                float al = alphas[m0w + mt * 16 + quad * 4 + r];
#pragma unroll
                for (int nt = 0; nt < 4; ++nt) oacc[mt][nt][r] *= al;
            }
#pragma unroll
        for (int ks = 0; ks < 2; ++ks) {
            bhalf8 pf0 = *reinterpret_cast<const bhalf8*>(&Ps[m0w + l15][ks * 32 + quad * 8]);
            bhalf8 pf1 = *reinterpret_cast<const bhalf8*>(&Ps[m0w + 16 + l15][ks * 32 + quad * 8]);
#pragma unroll
            for (int nt = 0; nt < 4; ++nt) {
                bhalf8 vf = *reinterpret_cast<const bhalf8*>(&Vs[n0v + nt * 16 + l15][ks * 32 + quad * 8]);
                oacc[0][nt] = __builtin_amdgcn_mfma_f32_16x16x32_bf16(pf0, vf, oacc[0][nt], 0, 0, 0);
                oacc[1][nt] = __builtin_amdgcn_mfma_f32_16x16x32_bf16(pf1, vf, oacc[1][nt], 0, 0, 0);
            }
        }
        __syncthreads();   // protect Ks/Vs re-staging
    }

    if ((tid & 3) == 0) lsum[srow_sm] = l_i;
    __syncthreads();
#pragma unroll
    for (int mt = 0; mt < 2; ++mt)
#pragma unroll
        for (int r = 0; r < 4; ++r) {
            int row = m0w + mt * 16 + quad * 4 + r;
            float inv = 1.0f / lsum[row];
#pragma unroll
            for (int nt = 0; nt < 4; ++nt)
                attn_out[qkbase + (long)row * 2048 + n0v + nt * 16 + l15] = oacc[mt][nt][r] * inv;
        }
}

// ---------------------------------------------------------------------------
// fq/fk/fv: silu (+affine for q/k) (+L2 norm over fd=512 for q/k) -> bf16
// ---------------------------------------------------------------------------
__global__ __launch_bounds__(128) void fqkv_kernel(
    const float* __restrict__ qkv, const float* __restrict__ qk_scale,
    const float* __restrict__ qk_offset, u16* __restrict__ out, int mode)
{
    int bid = blockIdx.x;
    int nh = bid & 3;
    int row = bid >> 2;
    const float* x = &qkv[(long)row * 6144 + mode * 2048 + nh * 512];
    __shared__ float red[128];
    float vals[4];
    float ss = 0.f;
#pragma unroll
    for (int ii = 0; ii < 4; ++ii) {
        int i = threadIdx.x + ii * 128;
        float v = x[i];
        float sg = 1.f / (1.f + expf(-v));
        float sv = v * sg;
        if (mode < 2) {
            int dcol = nh * 512 + i;
            sv = sv * qk_scale[dcol * 2 + mode] + qk_offset[dcol * 2 + mode];
        }
        vals[ii] = sv;
        ss += sv * sv;
    }
    float invn = 1.0f;
    if (mode < 2) {
        red[threadIdx.x] = ss; __syncthreads();
        for (int s_ = 64; s_ > 0; s_ >>= 1) {
            if (threadIdx.x < s_) red[threadIdx.x] += red[threadIdx.x + s_];
            __syncthreads();
        }
        invn = 1.0f / (sqrtf(red[0]) + 1e-12f);
    }
    u16* o = &out[(long)row * 2048 + nh * 512];
#pragma unroll
    for (int ii = 0; ii < 4; ++ii) o[threadIdx.x + ii * 128] = f2bf(vals[ii] * invn);
}

// ---------------------------------------------------------------------------
// fast-weight init: tile (4,512,512) x b=2 -> (8,512,512) fp32
// ---------------------------------------------------------------------------
__global__ void winit(const float* __restrict__ w0, const float* __restrict__ w1,
                      const float* __restrict__ w2, float* __restrict__ w0b,
                      float* __restrict__ w1b, float* __restrict__ w2b)
{
    long idx = (long)blockIdx.x * 256 + threadIdx.x;
    long src = ((idx >> 18) & 3) * 262144 + (idx & 262143);
    w0b[idx] = w0[src];
    w1b[idx] = w1[src];
    w2b[idx] = w2[src];
}

// ---------------------------------------------------------------------------
// scan elementwise 1 (fp32 temps in place; fv read as bf16)
// ---------------------------------------------------------------------------
__global__ void scan_ew1(const float* gate, const float* hpre, const float* dhb,
                         const u16* fvb, const float* lr, int c0,
                         float* T1, float* T2, float* T3, float* T4)
{
    long idx = (long)blockIdx.x * 256 + threadIdx.x;  // 8*1024*512
    int f = (int)(idx & 511);
    long r = idx >> 9;
    int ci = (int)(r & 1023);
    int z = (int)(r >> 10);
    int b_ = z >> 2, h = z & 3;
    long srow = (long)b_ * S + (long)c0 * CHUNK + ci;
    float g = gate[idx], hp = hpre[idx], dh = dhb[idx];
    float sg = 1.f / (1.f + expf(-g));
    float silu_g = g * sg;
    float hid = silu_g * hp;
    float dgate = dh * hp * (sg * (1.f + g * (1.f - sg)));
    float dhpre = dh * silu_g;
    float l0 = lr[srow * 12 + h];
    float l1 = lr[srow * 12 + 4 + h];
    float l2 = lr[srow * 12 + 8 + h];
    float fvv = bf2f(fvb[srow * 2048 + h * 512 + f]);
    T1[idx] = dgate * l0;
    T2[idx] = dhpre * l2;
    T3[idx] = fvv * l1;
    T4[idx] = hid;
}

// scan elementwise 2: T1 = silu(T1) * T2
__global__ void scan_ew2(float* T1, const float* T2)
{
    long idx = (long)blockIdx.x * 256 + threadIdx.x;
    float g = T1[idx];
    T1[idx] = g * (1.f / (1.f + expf(-g))) * T2[idx];
}

// ---------------------------------------------------------------------------
// ttt rmsnorm added into attn_out in place
// ---------------------------------------------------------------------------
__global__ __launch_bounds__(128) void ttt_norm_add(
    const float* __restrict__ ttt, const float* __restrict__ w, float* attnX)
{
    int bid = blockIdx.x;
    int h = bid & 3;
    int row = bid >> 2;
    const float* x = &ttt[(long)row * 2048 + h * 512];
    __shared__ float red[128];
    float v[4];
    float ss = 0.f;
#pragma unroll
    for (int ii = 0; ii < 4; ++ii) {
        v[ii] = x[threadIdx.x + ii * 128];
        ss += v[ii] * v[ii];
    }
    red[threadIdx.x] = ss; __syncthreads();
    for (int s_ = 64; s_ > 0; s_ >>= 1) {
        if (threadIdx.x < s_) red[threadIdx.x] += red[threadIdx.x + s_];
        __syncthreads();
    }
    float sc = rsqrtf(red[0] / 512.f + 1e-6f);
    float* o = &attnX[(long)row * 2048 + h * 512];
#pragma unroll
    for (int ii = 0; ii < 4; ++ii) {
        int i = threadIdx.x + ii * 128;
        o[i] = o[i] + v[ii] * sc * w[i];
    }
}

// ---------------------------------------------------------------------------
extern "C" void kernel_launch(void* const* d_in, const int* in_sizes, int n_in,
                              void* d_out, int out_size, void* d_ws, size_t ws_size,
                              hipStream_t stream)
{
    const float* hs        = (const float*)d_in[0];
    const float* Wqkv      = (const float*)d_in[1];
    const float* Wo        = (const float*)d_in[2];
    const float* q_norm_w  = (const float*)d_in[3];
    const float* k_norm_w  = (const float*)d_in[4];
    const float* w0        = (const float*)d_in[5];
    const float* w1        = (const float*)d_in[6];
    const float* w2        = (const float*)d_in[7];
    const float* lr_w      = (const float*)d_in[8];
    const float* lr_b      = (const float*)d_in[9];
    const float* qk_scale  = (const float*)d_in[10];
    const float* qk_offset = (const float*)d_in[11];
    const float* ttt_w     = (const float*)d_in[12];
    float* out = (float*)d_out;
    float* ws = (float*)d_ws;

    // ---- workspace (fp32 units), total 65,060,864 floats = 248.2 MiB -------
    const long F_QKV = 0;          // qkv fp32 (25,165,824); later:
    const long F_TTT = 0;          //   ttt fp32 (8,388,608)
    const long F_T1  = 8388608;    //   T1..T4 fp32 (4 x 4,194,304)
    const long F_T2  = 12582912;
    const long F_T3  = 16777216;
    const long F_T4  = 20971520;
    const long F_AQ  = 25165824;   // hs_b -> aq bf16 (4M fl) + vt bf16 (4M fl) -> fq_b | fk_b
    const long F_AK  = 33554432;   // Wqkv_b -> ak bf16 -> fv_b | hq_b | fkt
    const long F_ATT = 41943040;   // attX fp32 (8,388,608)
    const long F_TTa = 50331648;   // transposed bf16 temp A (2,097,152)
    const long F_TTb = 52428800;   // transposed bf16 temp B (2,097,152)
    const long F_W0  = 54525952;   // weights fp32 (3 x 2,097,152)
    const long F_W1  = 56623104;
    const long F_W2  = 58720256;
    const long F_W0B = 60817408;   // bf16 snapshots (4 x 1,048,576)
    const long F_W1B = 61865984;
    const long F_W2B = 62914560;
    const long F_W1T = 63963136;
    const long F_LR  = 65011712;   // end 65,060,864

    u16* hs_b   = (u16*)(ws + F_AQ);
    u16* wqkv_b = (u16*)(ws + F_AK);
    u16* aq_b   = (u16*)(ws + F_AQ);             // bf16, 8,388,608 elems = 4,194,304 floats
    u16* ak_b   = (u16*)(ws + F_AK);             // bf16, 8,388,608 elems = 4,194,304 floats
    u16* vt_b   = (u16*)(ws + F_AQ + 4194304);   // bf16, 8,388,608 elems; ends exactly at F_AK
    u16* fq_b   = (u16*)(ws + F_AQ);
    u16* fk_b   = (u16*)(ws + F_AQ + 4194304);
    u16* fv_b   = (u16*)(ws + F_AK);
    u16* hq_b   = (u16*)(ws + F_AK + 4194304);
    u16* fkt_b  = (u16*)(ws + F_AK + 6291456);
    u16* tta    = (u16*)(ws + F_TTa);
    u16* ttb    = (u16*)(ws + F_TTb);
    u16* w0b_u  = (u16*)(ws + F_W0B);
    u16* w1b_u  = (u16*)(ws + F_W1B);
    u16* w2b_u  = (u16*)(ws + F_W2B);
    u16* w1t_u  = (u16*)(ws + F_W1T);
    u16* x_b    = (u16*)(ws + F_T1);   // after scan
    u16* wo_b   = (u16*)(ws + F_T3);   // after scan

    // 1. qkv = hs @ Wqkv^T  (bf16 MFMA)
    cvt_bf16<<<8192, 256, 0, stream>>>(hs, hs_b, 8388608);
    cvt_bf16<<<12288, 256, 0, stream>>>(Wqkv, wqkv_b, 12582912);
    gemm_mfma<<<dim3(48, 32, 1), 256, 0, stream>>>(
        hs_b, 2048, 0, 0, wqkv_b, 2048, 0, 0, ws + F_QKV, 6144, 0, 0, 2048, 0);
    // 2. lr
    lr_kernel<<<4096, 256, 0, stream>>>(hs, lr_w, lr_b, ws + F_LR);
    // 3. rmsnorm + rope -> bf16 (overwrites hs_b / wqkv_b — they are dead)
    rmsnorm_rope<<<4096, 256, 0, stream>>>(ws + F_QKV, 0,    q_norm_w, aq_b);
    rmsnorm_rope<<<4096, 256, 0, stream>>>(ws + F_QKV, 2048, k_norm_w, ak_b);
    // 3b. V transpose for attention
    vt_prep<<<dim3(32, 2, 32), 256, 0, stream>>>(ws + F_QKV, vt_b);
    // 4. attention (bf16 MFMA)
    attn_mfma<<<dim3(32, 16, 2), 256, 0, stream>>>(aq_b, ak_b, vt_b, ws + F_ATT);
    // 5. fq/fk/fv bf16 (overwrite aq/vt/ak regions — dead after attention)
    fqkv_kernel<<<16384, 128, 0, stream>>>(ws + F_QKV, qk_scale, qk_offset, fq_b, 0);
    fqkv_kernel<<<16384, 128, 0, stream>>>(ws + F_QKV, qk_scale, qk_offset, fk_b, 1);
    fqkv_kernel<<<16384, 128, 0, stream>>>(ws + F_QKV, qk_scale, qk_offset, fv_b, 2);
    // 6. fast-weight init (fp32 masters)
    winit<<<8192, 256, 0, stream>>>(w0, w1, w2, ws + F_W0, ws + F_W1, ws + F_W2);

    for (int c0 = 0; c0 < 2; ++c0) {
        const long cOff = (long)c0 * 2097152;           // chunk offset in bf16 elems
        // bf16 snapshots of weights + w1^T
        cvt_bf16<<<2048, 256, 0, stream>>>(ws + F_W0, w0b_u, 2097152);
        cvt_bf16<<<2048, 256, 0, stream>>>(ws + F_W2, w2b_u, 2097152);
        transpose_cvt<float><<<dim3(8, 8, 8), 256, 0, stream>>>(
            ws + F_W1, 512, 1048576, 262144, w1t_u, 512, 1048576, 262144);
        // fk^T for the updates
        transpose_cvt<u16><<<dim3(8, 16, 8), 256, 0, stream>>>(
            fk_b + cOff, 2048, 4194304, 512, fkt_b, 1024, 2097152, 524288);
        // gate / hpre / dh
        gemm_mfma<<<dim3(4, 8, 8), 256, 0, stream>>>(
            fk_b + cOff, 2048, 4194304, 512, w0b_u, 512, 1048576, 262144,
            ws + F_T1, 512, 2097152, 524288, 512, 0);
        gemm_mfma<<<dim3(4, 8, 8), 256, 0, stream>>>(
            fk_b + cOff, 2048, 4194304, 512, w2b_u, 512, 1048576, 262144,
            ws + F_T2, 512, 2097152, 524288, 512, 0);
        gemm_mfma<<<dim3(4, 8, 8), 256, 0, stream>>>(
            fv_b + cOff, 2048, 4194304, 512, w1t_u, 512, 1048576, 262144,
            ws + F_T3, 512, 2097152, 524288, 512, 0);
        // elementwise
        scan_ew1<<<16384, 256, 0, stream>>>(ws + F_T1, ws + F_T2, ws + F_T3,
                                            fv_b, ws + F_LR, c0,
                                            ws + F_T1, ws + F_T2, ws + F_T3, ws + F_T4);
        // w0 / w2 updates: transpose T1,T2 then C += A^T-form MFMA
        transpose_cvt<float><<<dim3(8, 16, 8), 256, 0, stream>>>(
            ws + F_T1, 512, 2097152, 524288, tta, 1024, 2097152, 524288);
        transpose_cvt<float><<<dim3(8, 16, 8), 256, 0, stream>>>(
            ws + F_T2, 512, 2097152, 524288, ttb, 1024, 2097152, 524288);
        gemm_mfma<<<dim3(4, 4, 8), 256, 0, stream>>>(
            tta, 1024, 2097152, 524288, fkt_b, 1024, 2097152, 524288,
            ws + F_W0, 512, 1048576, 262144, 1024, 1);
        gemm_mfma<<<dim3(4, 4, 8), 256, 0, stream>>>(
            ttb, 1024, 2097152, 524288, fkt_b, 1024, 2097152, 524288,
            ws + F_W2, 512, 1048576, 262144, 1024, 1);
        // w1 update: transpose T3,T4
        transpose_cvt<float><<<dim3(8, 16, 8), 256, 0, stream>>>(
            ws + F_T3, 512, 2097152, 524288, tta, 1024, 2097152, 524288);
        transpose_cvt<float><<<dim3(8, 16, 8), 256, 0, stream>>>(
            ws + F_T4, 512, 2097152, 524288, ttb, 1024, 2097152, 524288);
        gemm_mfma<<<dim3(4, 4, 8), 256, 0, stream>>>(
            tta, 1024, 2097152, 524288, ttb, 1024, 2097152, 524288,
            ws + F_W1, 512, 1048576, 262144, 1024, 1);
        // query pass with updated weights
        cvt_bf16<<<2048, 256, 0, stream>>>(ws + F_W0, w0b_u, 2097152);
        cvt_bf16<<<2048, 256, 0, stream>>>(ws + F_W2, w2b_u, 2097152);
        cvt_bf16<<<2048, 256, 0, stream>>>(ws + F_W1, w1b_u, 2097152);
        gemm_mfma<<<dim3(4, 8, 8), 256, 0, stream>>>(
            fq_b + cOff, 2048, 4194304, 512, w0b_u, 512, 1048576, 262144,
            ws + F_T1, 512, 2097152, 524288, 512, 0);
        gemm_mfma<<<dim3(4, 8, 8), 256, 0, stream>>>(
            fq_b + cOff, 2048, 4194304, 512, w2b_u, 512, 1048576, 262144,
            ws + F_T2, 512, 2097152, 524288, 512, 0);
        scan_ew2<<<16384, 256, 0, stream>>>(ws + F_T1, ws + F_T2);
        cvt_bf16<<<4096, 256, 0, stream>>>(ws + F_T1, hq_b, 4194304);
        // oi = hq @ w1^T -> ttt (strided (b,s,NH,fd))
        gemm_mfma<<<dim3(4, 8, 8), 256, 0, stream>>>(
            hq_b, 512, 2097152, 524288, w1b_u, 512, 1048576, 262144,
            ws + F_TTT + cOff, 2048, 4194304, 512, 512, 0);
    }

    // 8. ttt rmsnorm + add into attX
    ttt_norm_add<<<16384, 128, 0, stream>>>(ws + F_TTT, ttt_w, ws + F_ATT);
    // 9. out = X @ Wo^T  (bf16 MFMA; X_b/Wo_b reuse dead T region)
    cvt_bf16<<<8192, 256, 0, stream>>>(ws + F_ATT, x_b, 8388608);
    cvt_bf16<<<4096, 256, 0, stream>>>(Wo, wo_b, 4194304);
    gemm_mfma<<<dim3(16, 32, 1), 256, 0, stream>>>(
        x_b, 2048, 0, 0, wo_b, 2048, 0, 0, out, 2048, 0, 0, 2048, 0);
}

// Round 4
// 1278.261 us; speedup vs baseline: 1.5642x; 1.0325x over previous
//
#include <hip/hip_runtime.h>
#include <hip/hip_bf16.h>
#include <math.h>

#define S 2048
#define NH 4
#define FD 512
#define CHUNK 1024
#define BASE_LR_INV -6.9072552373f

typedef unsigned short u16;
typedef unsigned int u32;
typedef short bhalf8 __attribute__((ext_vector_type(8)));   // 8 bf16 = 4 VGPRs
typedef float floatx4 __attribute__((ext_vector_type(4)));

__device__ __forceinline__ u16 f2bf(float f) {               // RNE fp32->bf16
    u32 x = __float_as_uint(f);
    return (u16)((x + 0x7FFFu + ((x >> 16) & 1u)) >> 16);
}
__device__ __forceinline__ float bf2f(u16 u) {
    return __uint_as_float(((u32)u) << 16);
}
__device__ __forceinline__ float ldval(const float* p) { return *p; }
__device__ __forceinline__ float ldval(const u16* p) { return bf2f(*p); }

// async global->LDS, 16B per lane. LDS dest must be wave-uniform base
// (HW writes base + lane*16); global src is per-lane.
__device__ __forceinline__ void gl_lds16(const u16* g, u16* l)
{
    __builtin_amdgcn_global_load_lds(
        (const __attribute__((address_space(1))) void*)g,
        (__attribute__((address_space(3))) void*)l, 16, 0, 0);
}

// ---------------------------------------------------------------------------
// bf16 MFMA GEMM:  C(fp32) = A @ B^T, A:(M,K) bf16 lda, B:(N,K) bf16 ldb.
// 128x128 block tile, 256 thr = 4 waves (2x2 of 64x64), BK=32,
// v_mfma_f32_16x16x32_bf16. Staging via global_load_lds width=16 into
// LINEAR LDS [128][32] (m97 structure). acc_flag: C += result.
// Batched: ptr += (z>>2)*offO + (z&3)*offI.  M,N mult of 128; K mult of 32.
// ---------------------------------------------------------------------------
__global__ __launch_bounds__(256) void gemm_mfma(
    const u16* __restrict__ A, int lda, long offAo, long offAi,
    const u16* __restrict__ B, int ldb, long offBo, long offBi,
    float* __restrict__ C, int ldc, long offCo, long offCi, int K, int acc_flag)
{
    int z = blockIdx.z;
    A += (long)(z >> 2) * offAo + (long)(z & 3) * offAi;
    B += (long)(z >> 2) * offBo + (long)(z & 3) * offBi;
    C += (long)(z >> 2) * offCo + (long)(z & 3) * offCi;
    __shared__ u16 As[128][32];   // linear: required by global_load_lds
    __shared__ u16 Bs[128][32];
    const int tid = threadIdx.x;
    const int wid = tid >> 6, lane = tid & 63;
    const int quad = lane >> 4, l15 = lane & 15;
    const int m0w = (wid >> 1) * 64, n0w = (wid & 1) * 64;
    const int row0 = blockIdx.y * 128, col0 = blockIdx.x * 128;
    // staging lane map: chunk = 16 rows x 32 cols (1 KiB); lane l -> row l>>2, col (l&3)*8
    const int srow = lane >> 2, scol = (lane & 3) * 8;
    const int ca = wid * 16, cb = (wid + 4) * 16;   // this wave's two chunk rows

    floatx4 acc[4][4];
#pragma unroll
    for (int a = 0; a < 4; ++a)
#pragma unroll
        for (int b = 0; b < 4; ++b) acc[a][b] = {0.f, 0.f, 0.f, 0.f};

    for (int kk = 0; kk < K; kk += 32) {
        // each wave stages 2 A-chunks + 2 B-chunks (4 x 1 KiB)
        gl_lds16(&A[(long)(row0 + ca + srow) * lda + kk + scol], &As[ca][0]);
        gl_lds16(&A[(long)(row0 + cb + srow) * lda + kk + scol], &As[cb][0]);
        gl_lds16(&B[(long)(col0 + ca + srow) * ldb + kk + scol], &Bs[ca][0]);
        gl_lds16(&B[(long)(col0 + cb + srow) * ldb + kk + scol], &Bs[cb][0]);
        __syncthreads();   // compiler emits s_waitcnt vmcnt(0) before barrier
        bhalf8 af[4], bf[4];
#pragma unroll
        for (int mt = 0; mt < 4; ++mt)
            af[mt] = *reinterpret_cast<const bhalf8*>(&As[m0w + mt * 16 + l15][quad * 8]);
#pragma unroll
        for (int nt = 0; nt < 4; ++nt)
            bf[nt] = *reinterpret_cast<const bhalf8*>(&Bs[n0w + nt * 16 + l15][quad * 8]);
#pragma unroll
        for (int mt = 0; mt < 4; ++mt)
#pragma unroll
            for (int nt = 0; nt < 4; ++nt)
                acc[mt][nt] = __builtin_amdgcn_mfma_f32_16x16x32_bf16(
                    af[mt], bf[nt], acc[mt][nt], 0, 0, 0);
        __syncthreads();
    }
#pragma unroll
    for (int mt = 0; mt < 4; ++mt)
#pragma unroll
        for (int nt = 0; nt < 4; ++nt) {
            int col = col0 + n0w + nt * 16 + l15;
#pragma unroll
            for (int r = 0; r < 4; ++r) {
                int row = row0 + m0w + mt * 16 + quad * 4 + r;
                long off = (long)row * ldc + col;
                float v = acc[mt][nt][r];
                C[off] = acc_flag ? (C[off] + v) : v;
            }
        }
}

// ---------------------------------------------------------------------------
// flat fp32 -> bf16 convert (n mult of 4)
// ---------------------------------------------------------------------------
__global__ __launch_bounds__(256) void cvt_bf16(
    const float* __restrict__ in, u16* __restrict__ out, long n)
{
    long i = ((long)blockIdx.x * 256 + threadIdx.x) * 4;
    if (i >= n) return;
    float4 v = *reinterpret_cast<const float4*>(&in[i]);
    ushort4 o;
    o.x = f2bf(v.x); o.y = f2bf(v.y); o.z = f2bf(v.z); o.w = f2bf(v.w);
    *reinterpret_cast<ushort4*>(&out[i]) = o;
}

// ---------------------------------------------------------------------------
// batched transpose + cvt: in[z] (R,C) ld=ldin  ->  out[z] (C,R) bf16 ld=ldout
// grid (C/64, R/64, 8)
// ---------------------------------------------------------------------------
template <typename TIN>
__global__ __launch_bounds__(256) void transpose_cvt(
    const TIN* __restrict__ in, int ldin, long inOo, long inOi,
    u16* __restrict__ out, int ldout, long outOo, long outOi)
{
    int z = blockIdx.z;
    in  += (long)(z >> 2) * inOo + (long)(z & 3) * inOi;
    out += (long)(z >> 2) * outOo + (long)(z & 3) * outOi;
    int r0 = blockIdx.y * 64, c0 = blockIdx.x * 64;
    __shared__ float t[64][65];
    for (int i = threadIdx.x; i < 4096; i += 256) {
        int r = i >> 6, c = i & 63;
        t[r][c] = ldval(&in[(long)(r0 + r) * ldin + c0 + c]);
    }
    __syncthreads();
    for (int i = threadIdx.x; i < 4096; i += 256) {
        int r = i >> 6, c = i & 63;
        out[(long)(c0 + r) * ldout + r0 + c] = f2bf(t[c][r]);
    }
}

// ---------------------------------------------------------------------------
// V transpose for attention: qkv V slice (b,s,h,128) fp32 -> vt (b,h,128,s) bf16
// grid (S/64, 128/64, b*16)
// ---------------------------------------------------------------------------
__global__ __launch_bounds__(256) void vt_prep(
    const float* __restrict__ qkv, u16* __restrict__ vt)
{
    int z = blockIdx.z;          // b*16 + h
    int b_ = z >> 4, h = z & 15;
    int s0 = blockIdx.x * 64, d0 = blockIdx.y * 64;
    __shared__ float t[64][65];
    const float* src = &qkv[(long)(b_ * S) * 6144 + 4096 + h * 128 + d0];
    for (int i = threadIdx.x; i < 4096; i += 256) {
        int r = i >> 6, c = i & 63;      // r: s, c: d
        t[r][c] = src[(long)(s0 + r) * 6144 + c];
    }
    __syncthreads();
    u16* dst = &vt[((long)z * 128 + d0) * 2048 + s0];
    for (int i = threadIdx.x; i < 4096; i += 256) {
        int r = i >> 6, c = i & 63;      // r: d, c: s
        dst[(long)r * 2048 + c] = f2bf(t[c][r]);
    }
}

// ---------------------------------------------------------------------------
// lr = softplus(hs @ lr_w^T + lr_b + BASE_LR_INV)  -> (4096, 12)
// ---------------------------------------------------------------------------
__global__ __launch_bounds__(256) void lr_kernel(
    const float* __restrict__ hs, const float* __restrict__ lr_w,
    const float* __restrict__ lr_b, float* __restrict__ lr)
{
    int row = blockIdx.x;
    __shared__ float hrow[2048];
    __shared__ float red[256];
    for (int i = threadIdx.x; i < 2048; i += 256) hrow[i] = hs[(long)row * 2048 + i];
    __syncthreads();
    for (int j = 0; j < 12; ++j) {
        float ss = 0.f;
        for (int i = threadIdx.x; i < 2048; i += 256) ss += hrow[i] * lr_w[(long)j * 2048 + i];
        red[threadIdx.x] = ss; __syncthreads();
        for (int s_ = 128; s_ > 0; s_ >>= 1) {
            if (threadIdx.x < s_) red[threadIdx.x] += red[threadIdx.x + s_];
            __syncthreads();
        }
        if (threadIdx.x == 0) {
            float x = red[0] + lr_b[j] + BASE_LR_INV;
            lr[(long)row * 12 + j] = (x > 20.f) ? x : log1pf(expf(x));
        }
        __syncthreads();
    }
}

// ---------------------------------------------------------------------------
// rmsnorm over d=2048 + RoPE per head (hd=128) -> packed bf16 (b,s,16,128)
// trig hoisted: only 64 distinct (si,t2) pairs per row -> LDS table
// ---------------------------------------------------------------------------
__global__ __launch_bounds__(256) void rmsnorm_rope(
    const float* __restrict__ qkv, int colOff, const float* __restrict__ w,
    u16* __restrict__ out)
{
    int row = blockIdx.x;            // b*s
    int si = row & (S - 1);
    const float* x = &qkv[(long)row * 6144 + colOff];
    __shared__ float xn[2048];
    __shared__ float red[256];
    __shared__ float cst[64], snt[64];
    if (threadIdx.x < 64) {
        float inv_freq = powf(500000.0f, -(float)threadIdx.x / 64.0f);
        float ang = (float)si * inv_freq;
        float sn, cs;
        sincosf(ang, &sn, &cs);
        cst[threadIdx.x] = cs;
        snt[threadIdx.x] = sn;
    }
    float ss = 0.f;
    for (int i = threadIdx.x; i < 2048; i += 256) { float v = x[i]; ss += v * v; }
    red[threadIdx.x] = ss; __syncthreads();
    for (int s_ = 128; s_ > 0; s_ >>= 1) {
        if (threadIdx.x < s_) red[threadIdx.x] += red[threadIdx.x + s_];
        __syncthreads();
    }
    float scale = rsqrtf(red[0] / 2048.f + 1e-6f);
    for (int i = threadIdx.x; i < 2048; i += 256) xn[i] = x[i] * scale * w[i];
    __syncthreads();
    for (int i = threadIdx.x; i < 2048; i += 256) {
        int tt = i & 127;
        int t2 = tt & 63;
        float cs = cst[t2], sn = snt[t2];
        float v;
        if (tt < 64) v = xn[i] * cs - xn[i + 64] * sn;
        else         v = xn[i] * cs + xn[i - 64] * sn;
        out[(long)row * 2048 + i] = f2bf(v);
    }
}

// ---------------------------------------------------------------------------
// Flash-style sliding-window causal attention, bf16 MFMA.
// Block: 64 q-rows x one head; 256 thr = 4 waves.
// QK^T: waves 2x2 over (32q x 32kv). PV: waves 2x2 over (32q x 64d).
// aq/ak: bf16 (b*s, 2048) with head at h*128. vt: bf16 (b,h,128,2048).
// ---------------------------------------------------------------------------
__global__ __launch_bounds__(256) void attn_mfma(
    const u16* __restrict__ aq, const u16* __restrict__ ak,
    const u16* __restrict__ vt, float* __restrict__ attn_out)
{
    const int qt = blockIdx.x;   // 0..31
    const int h  = blockIdx.y;   // 0..15
    const int b_ = blockIdx.z;   // 0..1
    const int q0 = qt * 64;
    const int tid = threadIdx.x;
    const int wid = tid >> 6, lane = tid & 63;
    const int quad = lane >> 4, l15 = lane & 15;
    const int m0w = (wid >> 1) * 32;      // q rows for this wave
    const int n0w = (wid & 1) * 32;       // kv cols (QK phase)
    const int n0v = (wid & 1) * 64;       // d cols (PV phase)
    const float scale = 0.088388347648318447f;

    __shared__ u16  Ks[64][136];   // K tile (also Q staging); 272B rows, 16B aligned
    __shared__ float Ss[64][67];   // scores; pad 67 -> conflict-free softmax reads
    __shared__ u16  Ps[64][72];    // P bf16; 144B rows
    __shared__ u16  Vs[128][72];   // V^T tile: [d][kv]
    __shared__ float alphas[64];
    __shared__ float lsum[64];

    const long qkbase = (long)(b_ * S + q0) * 2048 + h * 128;
    const long vtbase = ((long)(b_ * 16 + h)) * 128 * 2048;

    // ---- stage Q tile into Ks, hoist Q fragments into registers ----
    {
        int r = tid >> 2, c = (tid & 3) * 32;
        const u16* g = &aq[qkbase + (long)r * 2048 + c];
#pragma unroll
        for (int o = 0; o < 32; o += 8)
            *reinterpret_cast<uint4*>(&Ks[r][c + o]) = *reinterpret_cast<const uint4*>(g + o);
    }
    __syncthreads();
    bhalf8 qf[2][4];
#pragma unroll
    for (int mt = 0; mt < 2; ++mt)
#pragma unroll
        for (int ks = 0; ks < 4; ++ks)
            qf[mt][ks] = *reinterpret_cast<const bhalf8*>(&Ks[m0w + mt * 16 + l15][ks * 32 + quad * 8]);
    __syncthreads();

    floatx4 oacc[2][4];
#pragma unroll
    for (int mt = 0; mt < 2; ++mt)
#pragma unroll
        for (int nt = 0; nt < 4; ++nt) oacc[mt][nt] = {0.f, 0.f, 0.f, 0.f};
    float m_i = -3.4e38f, l_i = 0.f;           // row = tid>>2 (4 threads replicate)
    const int srow_sm = tid >> 2, scol_sm = (tid & 3) * 16;

    const int st = (qt >= 16) ? (qt - 16) : 0;
    for (int kt = st; kt <= qt; ++kt) {
        const int j0 = kt * 64;
        // stage K tile (64 x 128 bf16)
        {
            int r = tid >> 2, c = (tid & 3) * 32;
            const u16* g = &ak[(long)(b_ * S + j0) * 2048 + h * 128 + (long)r * 2048 + c];
#pragma unroll
            for (int o = 0; o < 32; o += 8)
                *reinterpret_cast<uint4*>(&Ks[r][c + o]) = *reinterpret_cast<const uint4*>(g + o);
        }
        // stage V^T tile (128 d-rows x 64 kv-cols bf16)
        {
            int r = tid >> 1, c = (tid & 1) * 32;
            const u16* g = &vt[vtbase + (long)r * 2048 + j0 + c];
#pragma unroll
            for (int o = 0; o < 32; o += 8)
                *reinterpret_cast<uint4*>(&Vs[r][c + o]) = *reinterpret_cast<const uint4*>(g + o);
        }
        __syncthreads();

        // ---- QK^T: 32x32 quadrant per wave ----
        floatx4 sacc[2][2];
#pragma unroll
        for (int mt = 0; mt < 2; ++mt)
#pragma unroll
            for (int nt = 0; nt < 2; ++nt) sacc[mt][nt] = {0.f, 0.f, 0.f, 0.f};
#pragma unroll
        for (int ks = 0; ks < 4; ++ks) {
            bhalf8 kf0 = *reinterpret_cast<const bhalf8*>(&Ks[n0w + l15][ks * 32 + quad * 8]);
            bhalf8 kf1 = *reinterpret_cast<const bhalf8*>(&Ks[n0w + 16 + l15][ks * 32 + quad * 8]);
            sacc[0][0] = __builtin_amdgcn_mfma_f32_16x16x32_bf16(qf[0][ks], kf0, sacc[0][0], 0, 0, 0);
            sacc[0][1] = __builtin_amdgcn_mfma_f32_16x16x32_bf16(qf[0][ks], kf1, sacc[0][1], 0, 0, 0);
            sacc[1][0] = __builtin_amdgcn_mfma_f32_16x16x32_bf16(qf[1][ks], kf0, sacc[1][0], 0, 0, 0);
            sacc[1][1] = __builtin_amdgcn_mfma_f32_16x16x32_bf16(qf[1][ks], kf1, sacc[1][1], 0, 0, 0);
        }
        // masked + scaled scores to LDS
#pragma unroll
        for (int mt = 0; mt < 2; ++mt)
#pragma unroll
            for (int nt = 0; nt < 2; ++nt)
#pragma unroll
                for (int r = 0; r < 4; ++r) {
                    int row = m0w + mt * 16 + quad * 4 + r;
                    int col = n0w + nt * 16 + l15;
                    int i_abs = q0 + row, j_abs = j0 + col;
                    bool valid = (j_abs <= i_abs) && (i_abs - j_abs < 1024);
                    Ss[row][col] = valid ? sacc[mt][nt][r] * scale : -3.4e38f;
                }
        __syncthreads();

        // ---- online softmax: 4 consecutive lanes per row ----
        {
            float sv[16];
            float mx = -3.4e38f;
#pragma unroll
            for (int j = 0; j < 16; ++j) {
                sv[j] = Ss[srow_sm][scol_sm + j];
                mx = fmaxf(mx, sv[j]);
            }
            mx = fmaxf(mx, __shfl_xor(mx, 1));
            mx = fmaxf(mx, __shfl_xor(mx, 2));
            float m_new = fmaxf(m_i, mx);
            float alpha = expf(m_i - m_new);     // -3.4e38 - finite -> 0; 0 when stale
            float psum = 0.f;
#pragma unroll
            for (int j = 0; j < 16; ++j) {
                float p = (sv[j] > -1e30f) ? expf(sv[j] - m_new) : 0.f;
                Ps[srow_sm][scol_sm + j] = f2bf(p);
                psum += p;
            }
            psum += __shfl_xor(psum, 1);
            psum += __shfl_xor(psum, 2);
            l_i = l_i * alpha + psum;
            m_i = m_new;
            if ((tid & 3) == 0) alphas[srow_sm] = alpha;
        }
        __syncthreads();

        // ---- rescale O, then PV MFMA ----
#pragma unroll
        for (int mt = 0; mt < 2; ++mt)
#pragma unroll
            for (int r = 0; r < 4; ++r) {
                float al = alphas[m0w + mt * 16 + quad * 4 + r];
#pragma unroll
                for (int nt = 0; nt < 4; ++nt) oacc[mt][nt][r] *= al;
            }
#pragma unroll
        for (int ks = 0; ks < 2; ++ks) {
            bhalf8 pf0 = *reinterpret_cast<const bhalf8*>(&Ps[m0w + l15][ks * 32 + quad * 8]);
            bhalf8 pf1 = *reinterpret_cast<const bhalf8*>(&Ps[m0w + 16 + l15][ks * 32 + quad * 8]);
#pragma unroll
            for (int nt = 0; nt < 4; ++nt) {
                bhalf8 vf = *reinterpret_cast<const bhalf8*>(&Vs[n0v + nt * 16 + l15][ks * 32 + quad * 8]);
                oacc[0][nt] = __builtin_amdgcn_mfma_f32_16x16x32_bf16(pf0, vf, oacc[0][nt], 0, 0, 0);
                oacc[1][nt] = __builtin_amdgcn_mfma_f32_16x16x32_bf16(pf1, vf, oacc[1][nt], 0, 0, 0);
            }
        }
        __syncthreads();   // protect Ks/Vs re-staging
    }

    if ((tid & 3) == 0) lsum[srow_sm] = l_i;
    __syncthreads();
#pragma unroll
    for (int mt = 0; mt < 2; ++mt)
#pragma unroll
        for (int r = 0; r < 4; ++r) {
            int row = m0w + mt * 16 + quad * 4 + r;
            float inv = 1.0f / lsum[row];
#pragma unroll
            for (int nt = 0; nt < 4; ++nt)
                attn_out[qkbase + (long)row * 2048 + n0v + nt * 16 + l15] = oacc[mt][nt][r] * inv;
        }
}

// ---------------------------------------------------------------------------
// fq/fk/fv: silu (+affine for q/k) (+L2 norm over fd=512 for q/k) -> bf16
// ---------------------------------------------------------------------------
__global__ __launch_bounds__(128) void fqkv_kernel(
    const float* __restrict__ qkv, const float* __restrict__ qk_scale,
    const float* __restrict__ qk_offset, u16* __restrict__ out, int mode)
{
    int bid = blockIdx.x;
    int nh = bid & 3;
    int row = bid >> 2;
    const float* x = &qkv[(long)row * 6144 + mode * 2048 + nh * 512];
    __shared__ float red[128];
    float vals[4];
    float ss = 0.f;
#pragma unroll
    for (int ii = 0; ii < 4; ++ii) {
        int i = threadIdx.x + ii * 128;
        float v = x[i];
        float sg = 1.f / (1.f + expf(-v));
        float sv = v * sg;
        if (mode < 2) {
            int dcol = nh * 512 + i;
            sv = sv * qk_scale[dcol * 2 + mode] + qk_offset[dcol * 2 + mode];
        }
        vals[ii] = sv;
        ss += sv * sv;
    }
    float invn = 1.0f;
    if (mode < 2) {
        red[threadIdx.x] = ss; __syncthreads();
        for (int s_ = 64; s_ > 0; s_ >>= 1) {
            if (threadIdx.x < s_) red[threadIdx.x] += red[threadIdx.x + s_];
            __syncthreads();
        }
        invn = 1.0f / (sqrtf(red[0]) + 1e-12f);
    }
    u16* o = &out[(long)row * 2048 + nh * 512];
#pragma unroll
    for (int ii = 0; ii < 4; ++ii) o[threadIdx.x + ii * 128] = f2bf(vals[ii] * invn);
}

// ---------------------------------------------------------------------------
// fast-weight init: tile (4,512,512) x b=2 -> (8,512,512) fp32
// ---------------------------------------------------------------------------
__global__ void winit(const float* __restrict__ w0, const float* __restrict__ w1,
                      const float* __restrict__ w2, float* __restrict__ w0b,
                      float* __restrict__ w1b, float* __restrict__ w2b)
{
    long idx = (long)blockIdx.x * 256 + threadIdx.x;
    long src = ((idx >> 18) & 3) * 262144 + (idx & 262143);
    w0b[idx] = w0[src];
    w1b[idx] = w1[src];
    w2b[idx] = w2[src];
}

// ---------------------------------------------------------------------------
// scan elementwise 1 (fp32 temps in place; fv read as bf16)
// ---------------------------------------------------------------------------
__global__ void scan_ew1(const float* gate, const float* hpre, const float* dhb,
                         const u16* fvb, const float* lr, int c0,
                         float* T1, float* T2, float* T3, float* T4)
{
    long idx = (long)blockIdx.x * 256 + threadIdx.x;  // 8*1024*512
    int f = (int)(idx & 511);
    long r = idx >> 9;
    int ci = (int)(r & 1023);
    int z = (int)(r >> 10);
    int b_ = z >> 2, h = z & 3;
    long srow = (long)b_ * S + (long)c0 * CHUNK + ci;
    float g = gate[idx], hp = hpre[idx], dh = dhb[idx];
    float sg = 1.f / (1.f + expf(-g));
    float silu_g = g * sg;
    float hid = silu_g * hp;
    float dgate = dh * hp * (sg * (1.f + g * (1.f - sg)));
    float dhpre = dh * silu_g;
    float l0 = lr[srow * 12 + h];
    float l1 = lr[srow * 12 + 4 + h];
    float l2 = lr[srow * 12 + 8 + h];
    float fvv = bf2f(fvb[srow * 2048 + h * 512 + f]);
    T1[idx] = dgate * l0;
    T2[idx] = dhpre * l2;
    T3[idx] = fvv * l1;
    T4[idx] = hid;
}

// scan elementwise 2: T1 = silu(T1) * T2
__global__ void scan_ew2(float* T1, const float* T2)
{
    long idx = (long)blockIdx.x * 256 + threadIdx.x;
    float g = T1[idx];
    T1[idx] = g * (1.f / (1.f + expf(-g))) * T2[idx];
}

// ---------------------------------------------------------------------------
// ttt rmsnorm added into attn_out in place
// ---------------------------------------------------------------------------
__global__ __launch_bounds__(128) void ttt_norm_add(
    const float* __restrict__ ttt, const float* __restrict__ w, float* attnX)
{
    int bid = blockIdx.x;
    int h = bid & 3;
    int row = bid >> 2;
    const float* x = &ttt[(long)row * 2048 + h * 512];
    __shared__ float red[128];
    float v[4];
    float ss = 0.f;
#pragma unroll
    for (int ii = 0; ii < 4; ++ii) {
        v[ii] = x[threadIdx.x + ii * 128];
        ss += v[ii] * v[ii];
    }
    red[threadIdx.x] = ss; __syncthreads();
    for (int s_ = 64; s_ > 0; s_ >>= 1) {
        if (threadIdx.x < s_) red[threadIdx.x] += red[threadIdx.x + s_];
        __syncthreads();
    }
    float sc = rsqrtf(red[0] / 512.f + 1e-6f);
    float* o = &attnX[(long)row * 2048 + h * 512];
#pragma unroll
    for (int ii = 0; ii < 4; ++ii) {
        int i = threadIdx.x + ii * 128;
        o[i] = o[i] + v[ii] * sc * w[i];
    }
}

// ---------------------------------------------------------------------------
extern "C" void kernel_launch(void* const* d_in, const int* in_sizes, int n_in,
                              void* d_out, int out_size, void* d_ws, size_t ws_size,
                              hipStream_t stream)
{
    const float* hs        = (const float*)d_in[0];
    const float* Wqkv      = (const float*)d_in[1];
    const float* Wo        = (const float*)d_in[2];
    const float* q_norm_w  = (const float*)d_in[3];
    const float* k_norm_w  = (const float*)d_in[4];
    const float* w0        = (const float*)d_in[5];
    const float* w1        = (const float*)d_in[6];
    const float* w2        = (const float*)d_in[7];
    const float* lr_w      = (const float*)d_in[8];
    const float* lr_b      = (const float*)d_in[9];
    const float* qk_scale  = (const float*)d_in[10];
    const float* qk_offset = (const float*)d_in[11];
    const float* ttt_w     = (const float*)d_in[12];
    float* out = (float*)d_out;
    float* ws = (float*)d_ws;

    // ---- workspace (fp32 units), total 65,060,864 floats = 248.2 MiB -------
    const long F_QKV = 0;          // qkv fp32 (25,165,824); later:
    const long F_TTT = 0;          //   ttt fp32 (8,388,608)
    const long F_T1  = 8388608;    //   T1..T4 fp32 (4 x 4,194,304)
    const long F_T2  = 12582912;
    const long F_T3  = 16777216;
    const long F_T4  = 20971520;
    const long F_AQ  = 25165824;   // hs_b -> aq bf16 (4M fl) + vt bf16 (4M fl) -> fq_b | fk_b
    const long F_AK  = 33554432;   // Wqkv_b -> ak bf16 -> fv_b | hq_b | fkt
    const long F_ATT = 41943040;   // attX fp32 (8,388,608)
    const long F_TTa = 50331648;   // transposed bf16 temp A (2,097,152)
    const long F_TTb = 52428800;   // transposed bf16 temp B (2,097,152)
    const long F_W0  = 54525952;   // weights fp32 (3 x 2,097,152)
    const long F_W1  = 56623104;
    const long F_W2  = 58720256;
    const long F_W0B = 60817408;   // bf16 snapshots (4 x 1,048,576)
    const long F_W1B = 61865984;
    const long F_W2B = 62914560;
    const long F_W1T = 63963136;
    const long F_LR  = 65011712;   // end 65,060,864

    u16* hs_b   = (u16*)(ws + F_AQ);
    u16* wqkv_b = (u16*)(ws + F_AK);
    u16* aq_b   = (u16*)(ws + F_AQ);             // bf16, 8,388,608 elems = 4,194,304 floats
    u16* ak_b   = (u16*)(ws + F_AK);             // bf16, 8,388,608 elems = 4,194,304 floats
    u16* vt_b   = (u16*)(ws + F_AQ + 4194304);   // bf16, 8,388,608 elems; ends exactly at F_AK
    u16* fq_b   = (u16*)(ws + F_AQ);
    u16* fk_b   = (u16*)(ws + F_AQ + 4194304);
    u16* fv_b   = (u16*)(ws + F_AK);
    u16* hq_b   = (u16*)(ws + F_AK + 4194304);
    u16* fkt_b  = (u16*)(ws + F_AK + 6291456);
    u16* tta    = (u16*)(ws + F_TTa);
    u16* ttb    = (u16*)(ws + F_TTb);
    u16* w0b_u  = (u16*)(ws + F_W0B);
    u16* w1b_u  = (u16*)(ws + F_W1B);
    u16* w2b_u  = (u16*)(ws + F_W2B);
    u16* w1t_u  = (u16*)(ws + F_W1T);
    u16* x_b    = (u16*)(ws + F_T1);   // after scan
    u16* wo_b   = (u16*)(ws + F_T3);   // after scan

    // 1. qkv = hs @ Wqkv^T  (bf16 MFMA)
    cvt_bf16<<<8192, 256, 0, stream>>>(hs, hs_b, 8388608);
    cvt_bf16<<<12288, 256, 0, stream>>>(Wqkv, wqkv_b, 12582912);
    gemm_mfma<<<dim3(48, 32, 1), 256, 0, stream>>>(
        hs_b, 2048, 0, 0, wqkv_b, 2048, 0, 0, ws + F_QKV, 6144, 0, 0, 2048, 0);
    // 2. lr
    lr_kernel<<<4096, 256, 0, stream>>>(hs, lr_w, lr_b, ws + F_LR);
    // 3. rmsnorm + rope -> bf16 (overwrites hs_b / wqkv_b — they are dead)
    rmsnorm_rope<<<4096, 256, 0, stream>>>(ws + F_QKV, 0,    q_norm_w, aq_b);
    rmsnorm_rope<<<4096, 256, 0, stream>>>(ws + F_QKV, 2048, k_norm_w, ak_b);
    // 3b. V transpose for attention
    vt_prep<<<dim3(32, 2, 32), 256, 0, stream>>>(ws + F_QKV, vt_b);
    // 4. attention (bf16 MFMA)
    attn_mfma<<<dim3(32, 16, 2), 256, 0, stream>>>(aq_b, ak_b, vt_b, ws + F_ATT);
    // 5. fq/fk/fv bf16 (overwrite aq/vt/ak regions — dead after attention)
    fqkv_kernel<<<16384, 128, 0, stream>>>(ws + F_QKV, qk_scale, qk_offset, fq_b, 0);
    fqkv_kernel<<<16384, 128, 0, stream>>>(ws + F_QKV, qk_scale, qk_offset, fk_b, 1);
    fqkv_kernel<<<16384, 128, 0, stream>>>(ws + F_QKV, qk_scale, qk_offset, fv_b, 2);
    // 6. fast-weight init (fp32 masters)
    winit<<<8192, 256, 0, stream>>>(w0, w1, w2, ws + F_W0, ws + F_W1, ws + F_W2);

    for (int c0 = 0; c0 < 2; ++c0) {
        const long cOff = (long)c0 * 2097152;           // chunk offset in bf16 elems
        // bf16 snapshots of weights + w1^T
        cvt_bf16<<<2048, 256, 0, stream>>>(ws + F_W0, w0b_u, 2097152);
        cvt_bf16<<<2048, 256, 0, stream>>>(ws + F_W2, w2b_u, 2097152);
        transpose_cvt<float><<<dim3(8, 8, 8), 256, 0, stream>>>(
            ws + F_W1, 512, 1048576, 262144, w1t_u, 512, 1048576, 262144);
        // fk^T for the updates
        transpose_cvt<u16><<<dim3(8, 16, 8), 256, 0, stream>>>(
            fk_b + cOff, 2048, 4194304, 512, fkt_b, 1024, 2097152, 524288);
        // gate / hpre / dh
        gemm_mfma<<<dim3(4, 8, 8), 256, 0, stream>>>(
            fk_b + cOff, 2048, 4194304, 512, w0b_u, 512, 1048576, 262144,
            ws + F_T1, 512, 2097152, 524288, 512, 0);
        gemm_mfma<<<dim3(4, 8, 8), 256, 0, stream>>>(
            fk_b + cOff, 2048, 4194304, 512, w2b_u, 512, 1048576, 262144,
            ws + F_T2, 512, 2097152, 524288, 512, 0);
        gemm_mfma<<<dim3(4, 8, 8), 256, 0, stream>>>(
            fv_b + cOff, 2048, 4194304, 512, w1t_u, 512, 1048576, 262144,
            ws + F_T3, 512, 2097152, 524288, 512, 0);
        // elementwise
        scan_ew1<<<16384, 256, 0, stream>>>(ws + F_T1, ws + F_T2, ws + F_T3,
                                            fv_b, ws + F_LR, c0,
                                            ws + F_T1, ws + F_T2, ws + F_T3, ws + F_T4);
        // w0 / w2 updates: transpose T1,T2 then C += A^T-form MFMA
        transpose_cvt<float><<<dim3(8, 16, 8), 256, 0, stream>>>(
            ws + F_T1, 512, 2097152, 524288, tta, 1024, 2097152, 524288);
        transpose_cvt<float><<<dim3(8, 16, 8), 256, 0, stream>>>(
            ws + F_T2, 512, 2097152, 524288, ttb, 1024, 2097152, 524288);
        gemm_mfma<<<dim3(4, 4, 8), 256, 0, stream>>>(
            tta, 1024, 2097152, 524288, fkt_b, 1024, 2097152, 524288,
            ws + F_W0, 512, 1048576, 262144, 1024, 1);
        gemm_mfma<<<dim3(4, 4, 8), 256, 0, stream>>>(
            ttb, 1024, 2097152, 524288, fkt_b, 1024, 2097152, 524288,
            ws + F_W2, 512, 1048576, 262144, 1024, 1);
        // w1 update: transpose T3,T4
        transpose_cvt<float><<<dim3(8, 16, 8), 256, 0, stream>>>(
            ws + F_T3, 512, 2097152, 524288, tta, 1024, 2097152, 524288);
        transpose_cvt<float><<<dim3(8, 16, 8), 256, 0, stream>>>(
            ws + F_T4, 512, 2097152, 524288, ttb, 1024, 2097152, 524288);
        gemm_mfma<<<dim3(4, 4, 8), 256, 0, stream>>>(
            tta, 1024, 2097152, 524288, ttb, 1024, 2097152, 524288,
            ws + F_W1, 512, 1048576, 262144, 1024, 1);
        // query pass with updated weights
        cvt_bf16<<<2048, 256, 0, stream>>>(ws + F_W0, w0b_u, 2097152);
        cvt_bf16<<<2048, 256, 0, stream>>>(ws + F_W2, w2b_u, 2097152);
        cvt_bf16<<<2048, 256, 0, stream>>>(ws + F_W1, w1b_u, 2097152);
        gemm_mfma<<<dim3(4, 8, 8), 256, 0, stream>>>(
            fq_b + cOff, 2048, 4194304, 512, w0b_u, 512, 1048576, 262144,
            ws + F_T1, 512, 2097152, 524288, 512, 0);
        gemm_mfma<<<dim3(4, 8, 8), 256, 0, stream>>>(
            fq_b + cOff, 2048, 4194304, 512, w2b_u, 512, 1048576, 262144,
            ws + F_T2, 512, 2097152, 524288, 512, 0);
        scan_ew2<<<16384, 256, 0, stream>>>(ws + F_T1, ws + F_T2);
        cvt_bf16<<<4096, 256, 0, stream>>>(ws + F_T1, hq_b, 4194304);
        // oi = hq @ w1^T -> ttt (strided (b,s,NH,fd))
        gemm_mfma<<<dim3(4, 8, 8), 256, 0, stream>>>(
            hq_b, 512, 2097152, 524288, w1b_u, 512, 1048576, 262144,
            ws + F_TTT + cOff, 2048, 4194304, 512, 512, 0);
    }

    // 8. ttt rmsnorm + add into attX
    ttt_norm_add<<<16384, 128, 0, stream>>>(ws + F_TTT, ttt_w, ws + F_ATT);
    // 9. out = X @ Wo^T  (bf16 MFMA; X_b/Wo_b reuse dead T region)
    cvt_bf16<<<8192, 256, 0, stream>>>(ws + F_ATT, x_b, 8388608);
    cvt_bf16<<<4096, 256, 0, stream>>>(Wo, wo_b, 4194304);
    gemm_mfma<<<dim3(16, 32, 1), 256, 0, stream>>>(
        x_b, 2048, 0, 0, wo_b, 2048, 0, 0, out, 2048, 0, 0, 2048, 0);
}

// Round 5
// 1159.567 us; speedup vs baseline: 1.7243x; 1.1024x over previous
//
#include <hip/hip_runtime.h>
#include <hip/hip_bf16.h>
#include <math.h>

#define S 2048
#define NH 4
#define FD 512
#define CHUNK 1024
#define BASE_LR_INV -6.9072552373f

typedef unsigned short u16;
typedef unsigned int u32;
typedef short bhalf8 __attribute__((ext_vector_type(8)));   // 8 bf16 = 4 VGPRs
typedef float floatx4 __attribute__((ext_vector_type(4)));

__device__ __forceinline__ u16 f2bf(float f) {               // RNE fp32->bf16
    u32 x = __float_as_uint(f);
    return (u16)((x + 0x7FFFu + ((x >> 16) & 1u)) >> 16);
}
__device__ __forceinline__ float bf2f(u16 u) {
    return __uint_as_float(((u32)u) << 16);
}
__device__ __forceinline__ float ldval(const float* p) { return *p; }
__device__ __forceinline__ float ldval(const u16* p) { return bf2f(*p); }

// async global->LDS, 16B per lane. LDS dest must be wave-uniform base
// (HW writes base + lane*16); global src is per-lane.
__device__ __forceinline__ void gl_lds16(const u16* g, u16* l)
{
    __builtin_amdgcn_global_load_lds(
        (const __attribute__((address_space(1))) void*)g,
        (__attribute__((address_space(3))) void*)l, 16, 0, 0);
}

// ---------------------------------------------------------------------------
// bf16 MFMA GEMM:  C(fp32) = A @ B^T, A:(M,K) bf16 lda, B:(N,K) bf16 ldb.
// 128x128 block tile, 256 thr = 4 waves (2x2 of 64x64), BK=32, double-buffered
// LDS with global_load_lds prefetch (T3 minimum 2-phase: issue next-tile loads
// BEFORE computing current tile; one barrier per K-step drains vmcnt).
// acc_flag: C += result. Batched: ptr += (z>>2)*offO + (z&3)*offI.
// M,N mult of 128; K mult of 64.
// ---------------------------------------------------------------------------
__global__ __launch_bounds__(256) void gemm_mfma(
    const u16* __restrict__ A, int lda, long offAo, long offAi,
    const u16* __restrict__ B, int ldb, long offBo, long offBi,
    float* __restrict__ C, int ldc, long offCo, long offCi, int K, int acc_flag)
{
    int z = blockIdx.z;
    A += (long)(z >> 2) * offAo + (long)(z & 3) * offAi;
    B += (long)(z >> 2) * offBo + (long)(z & 3) * offBi;
    C += (long)(z >> 2) * offCo + (long)(z & 3) * offCi;
    __shared__ u16 As0[128][32], Bs0[128][32];   // linear: required by global_load_lds
    __shared__ u16 As1[128][32], Bs1[128][32];
    const int tid = threadIdx.x;
    const int wid = tid >> 6, lane = tid & 63;
    const int quad = lane >> 4, l15 = lane & 15;
    const int m0w = (wid >> 1) * 64, n0w = (wid & 1) * 64;
    const int row0 = blockIdx.y * 128, col0 = blockIdx.x * 128;
    // staging lane map: chunk = 16 rows x 32 cols (1 KiB); lane l -> row l>>2, col (l&3)*8
    const int srow = lane >> 2, scol = (lane & 3) * 8;
    const int ca = wid * 16, cb = (wid + 4) * 16;   // this wave's two chunk rows

    const u16* gA0 = &A[(long)(row0 + ca + srow) * lda + scol];
    const u16* gA1 = &A[(long)(row0 + cb + srow) * lda + scol];
    const u16* gB0 = &B[(long)(col0 + ca + srow) * ldb + scol];
    const u16* gB1 = &B[(long)(col0 + cb + srow) * ldb + scol];

    floatx4 acc[4][4];
#pragma unroll
    for (int a = 0; a < 4; ++a)
#pragma unroll
        for (int b = 0; b < 4; ++b) acc[a][b] = {0.f, 0.f, 0.f, 0.f};

#define GSTAGE(AS, BS, kk) do { \
    gl_lds16(gA0 + (kk), &AS[ca][0]); \
    gl_lds16(gA1 + (kk), &AS[cb][0]); \
    gl_lds16(gB0 + (kk), &BS[ca][0]); \
    gl_lds16(gB1 + (kk), &BS[cb][0]); } while (0)

#define GCOMP(AS, BS) do { \
    bhalf8 af[4], bf[4]; \
    _Pragma("unroll") \
    for (int mt = 0; mt < 4; ++mt) \
        af[mt] = *reinterpret_cast<const bhalf8*>(&AS[m0w + mt * 16 + l15][quad * 8]); \
    _Pragma("unroll") \
    for (int nt = 0; nt < 4; ++nt) \
        bf[nt] = *reinterpret_cast<const bhalf8*>(&BS[n0w + nt * 16 + l15][quad * 8]); \
    _Pragma("unroll") \
    for (int mt = 0; mt < 4; ++mt) \
        _Pragma("unroll") \
        for (int nt = 0; nt < 4; ++nt) \
            acc[mt][nt] = __builtin_amdgcn_mfma_f32_16x16x32_bf16( \
                af[mt], bf[nt], acc[mt][nt], 0, 0, 0); } while (0)

    const int nt = K >> 5;          // even: K % 64 == 0
    GSTAGE(As0, Bs0, 0);
    for (int t = 0; t < nt; t += 2) {
        __syncthreads();            // drains vmcnt: buf0 ready; prior buf1 reads done
        GSTAGE(As1, Bs1, (t + 1) * 32);   // prefetch flies under compute
        GCOMP(As0, Bs0);
        __syncthreads();            // drains vmcnt: buf1 ready; buf0 reads done
        if (t + 2 < nt) GSTAGE(As0, Bs0, (t + 2) * 32);
        GCOMP(As1, Bs1);
    }
#undef GSTAGE
#undef GCOMP

#pragma unroll
    for (int mt = 0; mt < 4; ++mt)
#pragma unroll
        for (int nt = 0; nt < 4; ++nt) {
            int col = col0 + n0w + nt * 16 + l15;
#pragma unroll
            for (int r = 0; r < 4; ++r) {
                int row = row0 + m0w + mt * 16 + quad * 4 + r;
                long off = (long)row * ldc + col;
                float v = acc[mt][nt][r];
                C[off] = acc_flag ? (C[off] + v) : v;
            }
        }
}

// ---------------------------------------------------------------------------
// flat fp32 -> bf16 convert (n mult of 4)
// ---------------------------------------------------------------------------
__global__ __launch_bounds__(256) void cvt_bf16(
    const float* __restrict__ in, u16* __restrict__ out, long n)
{
    long i = ((long)blockIdx.x * 256 + threadIdx.x) * 4;
    if (i >= n) return;
    float4 v = *reinterpret_cast<const float4*>(&in[i]);
    ushort4 o;
    o.x = f2bf(v.x); o.y = f2bf(v.y); o.z = f2bf(v.z); o.w = f2bf(v.w);
    *reinterpret_cast<ushort4*>(&out[i]) = o;
}

// ---------------------------------------------------------------------------
// batched transpose + cvt: in[z] (R,C) ld=ldin  ->  out[z] (C,R) bf16 ld=ldout
// grid (C/64, R/64, 8)
// ---------------------------------------------------------------------------
template <typename TIN>
__global__ __launch_bounds__(256) void transpose_cvt(
    const TIN* __restrict__ in, int ldin, long inOo, long inOi,
    u16* __restrict__ out, int ldout, long outOo, long outOi)
{
    int z = blockIdx.z;
    in  += (long)(z >> 2) * inOo + (long)(z & 3) * inOi;
    out += (long)(z >> 2) * outOo + (long)(z & 3) * outOi;
    int r0 = blockIdx.y * 64, c0 = blockIdx.x * 64;
    __shared__ float t[64][65];
    for (int i = threadIdx.x; i < 4096; i += 256) {
        int r = i >> 6, c = i & 63;
        t[r][c] = ldval(&in[(long)(r0 + r) * ldin + c0 + c]);
    }
    __syncthreads();
    for (int i = threadIdx.x; i < 4096; i += 256) {
        int r = i >> 6, c = i & 63;
        out[(long)(c0 + r) * ldout + r0 + c] = f2bf(t[c][r]);
    }
}

// ---------------------------------------------------------------------------
// V transpose for attention: qkv V slice (b,s,h,128) fp32 -> vt (b,h,128,s) bf16
// grid (S/64, 128/64, b*16)
// ---------------------------------------------------------------------------
__global__ __launch_bounds__(256) void vt_prep(
    const float* __restrict__ qkv, u16* __restrict__ vt)
{
    int z = blockIdx.z;          // b*16 + h
    int b_ = z >> 4, h = z & 15;
    int s0 = blockIdx.x * 64, d0 = blockIdx.y * 64;
    __shared__ float t[64][65];
    const float* src = &qkv[(long)(b_ * S) * 6144 + 4096 + h * 128 + d0];
    for (int i = threadIdx.x; i < 4096; i += 256) {
        int r = i >> 6, c = i & 63;      // r: s, c: d
        t[r][c] = src[(long)(s0 + r) * 6144 + c];
    }
    __syncthreads();
    u16* dst = &vt[((long)z * 128 + d0) * 2048 + s0];
    for (int i = threadIdx.x; i < 4096; i += 256) {
        int r = i >> 6, c = i & 63;      // r: d, c: s
        dst[(long)r * 2048 + c] = f2bf(t[c][r]);
    }
}

// ---------------------------------------------------------------------------
// lr = softplus(hs @ lr_w^T + lr_b + BASE_LR_INV)  -> (4096, 12)
// one wave per output j (striped); shuffle reduce, single barrier
// ---------------------------------------------------------------------------
__global__ __launch_bounds__(256) void lr_kernel(
    const float* __restrict__ hs, const float* __restrict__ lr_w,
    const float* __restrict__ lr_b, float* __restrict__ lr)
{
    int row = blockIdx.x;
    __shared__ float hrow[2048];
    for (int i = threadIdx.x; i < 2048; i += 256) hrow[i] = hs[(long)row * 2048 + i];
    __syncthreads();
    int wid = threadIdx.x >> 6, lane = threadIdx.x & 63;
    for (int j = wid; j < 12; j += 4) {
        const float* wrow = &lr_w[(long)j * 2048];
        float ss = 0.f;
        for (int i = lane; i < 2048; i += 64) ss += hrow[i] * wrow[i];
#pragma unroll
        for (int off = 32; off > 0; off >>= 1) ss += __shfl_down(ss, off);
        if (lane == 0) {
            float x = ss + lr_b[j] + BASE_LR_INV;
            lr[(long)row * 12 + j] = (x > 20.f) ? x : log1pf(expf(x));
        }
    }
}

// ---------------------------------------------------------------------------
// rmsnorm over d=2048 + RoPE per head (hd=128) -> packed bf16 (b,s,16,128)
// trig hoisted: only 64 distinct (si,t2) pairs per row -> LDS table
// ---------------------------------------------------------------------------
__global__ __launch_bounds__(256) void rmsnorm_rope(
    const float* __restrict__ qkv, int colOff, const float* __restrict__ w,
    u16* __restrict__ out)
{
    int row = blockIdx.x;            // b*s
    int si = row & (S - 1);
    const float* x = &qkv[(long)row * 6144 + colOff];
    __shared__ float xn[2048];
    __shared__ float red[256];
    __shared__ float cst[64], snt[64];
    if (threadIdx.x < 64) {
        float inv_freq = powf(500000.0f, -(float)threadIdx.x / 64.0f);
        float ang = (float)si * inv_freq;
        float sn, cs;
        sincosf(ang, &sn, &cs);
        cst[threadIdx.x] = cs;
        snt[threadIdx.x] = sn;
    }
    float ss = 0.f;
    for (int i = threadIdx.x; i < 2048; i += 256) { float v = x[i]; ss += v * v; }
    red[threadIdx.x] = ss; __syncthreads();
    for (int s_ = 128; s_ > 0; s_ >>= 1) {
        if (threadIdx.x < s_) red[threadIdx.x] += red[threadIdx.x + s_];
        __syncthreads();
    }
    float scale = rsqrtf(red[0] / 2048.f + 1e-6f);
    for (int i = threadIdx.x; i < 2048; i += 256) xn[i] = x[i] * scale * w[i];
    __syncthreads();
    for (int i = threadIdx.x; i < 2048; i += 256) {
        int tt = i & 127;
        int t2 = tt & 63;
        float cs = cst[t2], sn = snt[t2];
        float v;
        if (tt < 64) v = xn[i] * cs - xn[i + 64] * sn;
        else         v = xn[i] * cs + xn[i - 64] * sn;
        out[(long)row * 2048 + i] = f2bf(v);
    }
}

// ---------------------------------------------------------------------------
// Flash-style sliding-window causal attention, bf16 MFMA.
// Block: 64 q-rows x one head; 256 thr = 4 waves.
// QK^T: waves 2x2 over (32q x 32kv). PV: waves 2x2 over (32q x 64d).
// aq/ak: bf16 (b*s, 2048) with head at h*128. vt: bf16 (b,h,128,2048).
// ---------------------------------------------------------------------------
__global__ __launch_bounds__(256) void attn_mfma(
    const u16* __restrict__ aq, const u16* __restrict__ ak,
    const u16* __restrict__ vt, float* __restrict__ attn_out)
{
    const int qt = blockIdx.x;   // 0..31
    const int h  = blockIdx.y;   // 0..15
    const int b_ = blockIdx.z;   // 0..1
    const int q0 = qt * 64;
    const int tid = threadIdx.x;
    const int wid = tid >> 6, lane = tid & 63;
    const int quad = lane >> 4, l15 = lane & 15;
    const int m0w = (wid >> 1) * 32;      // q rows for this wave
    const int n0w = (wid & 1) * 32;       // kv cols (QK phase)
    const int n0v = (wid & 1) * 64;       // d cols (PV phase)
    const float scale = 0.088388347648318447f;

    __shared__ u16  Ks[64][136];   // K tile (also Q staging); 272B rows, 16B aligned
    __shared__ float Ss[64][67];   // scores; pad 67 -> conflict-free softmax reads
    __shared__ u16  Ps[64][72];    // P bf16; 144B rows
    __shared__ u16  Vs[128][72];   // V^T tile: [d][kv]
    __shared__ float alphas[64];
    __shared__ float lsum[64];

    const long qkbase = (long)(b_ * S + q0) * 2048 + h * 128;
    const long vtbase = ((long)(b_ * 16 + h)) * 128 * 2048;

    // ---- stage Q tile into Ks, hoist Q fragments into registers ----
    {
        int r = tid >> 2, c = (tid & 3) * 32;
        const u16* g = &aq[qkbase + (long)r * 2048 + c];
#pragma unroll
        for (int o = 0; o < 32; o += 8)
            *reinterpret_cast<uint4*>(&Ks[r][c + o]) = *reinterpret_cast<const uint4*>(g + o);
    }
    __syncthreads();
    bhalf8 qf[2][4];
#pragma unroll
    for (int mt = 0; mt < 2; ++mt)
#pragma unroll
        for (int ks = 0; ks < 4; ++ks)
            qf[mt][ks] = *reinterpret_cast<const bhalf8*>(&Ks[m0w + mt * 16 + l15][ks * 32 + quad * 8]);
    __syncthreads();

    floatx4 oacc[2][4];
#pragma unroll
    for (int mt = 0; mt < 2; ++mt)
#pragma unroll
        for (int nt = 0; nt < 4; ++nt) oacc[mt][nt] = {0.f, 0.f, 0.f, 0.f};
    float m_i = -3.4e38f, l_i = 0.f;           // row = tid>>2 (4 threads replicate)
    const int srow_sm = tid >> 2, scol_sm = (tid & 3) * 16;

    const int st = (qt >= 16) ? (qt - 16) : 0;
    for (int kt = st; kt <= qt; ++kt) {
        const int j0 = kt * 64;
        // stage K tile (64 x 128 bf16)
        {
            int r = tid >> 2, c = (tid & 3) * 32;
            const u16* g = &ak[(long)(b_ * S + j0) * 2048 + h * 128 + (long)r * 2048 + c];
#pragma unroll
            for (int o = 0; o < 32; o += 8)
                *reinterpret_cast<uint4*>(&Ks[r][c + o]) = *reinterpret_cast<const uint4*>(g + o);
        }
        // stage V^T tile (128 d-rows x 64 kv-cols bf16)
        {
            int r = tid >> 1, c = (tid & 1) * 32;
            const u16* g = &vt[vtbase + (long)r * 2048 + j0 + c];
#pragma unroll
            for (int o = 0; o < 32; o += 8)
                *reinterpret_cast<uint4*>(&Vs[r][c + o]) = *reinterpret_cast<const uint4*>(g + o);
        }
        __syncthreads();

        // ---- QK^T: 32x32 quadrant per wave ----
        floatx4 sacc[2][2];
#pragma unroll
        for (int mt = 0; mt < 2; ++mt)
#pragma unroll
            for (int nt = 0; nt < 2; ++nt) sacc[mt][nt] = {0.f, 0.f, 0.f, 0.f};
#pragma unroll
        for (int ks = 0; ks < 4; ++ks) {
            bhalf8 kf0 = *reinterpret_cast<const bhalf8*>(&Ks[n0w + l15][ks * 32 + quad * 8]);
            bhalf8 kf1 = *reinterpret_cast<const bhalf8*>(&Ks[n0w + 16 + l15][ks * 32 + quad * 8]);
            sacc[0][0] = __builtin_amdgcn_mfma_f32_16x16x32_bf16(qf[0][ks], kf0, sacc[0][0], 0, 0, 0);
            sacc[0][1] = __builtin_amdgcn_mfma_f32_16x16x32_bf16(qf[0][ks], kf1, sacc[0][1], 0, 0, 0);
            sacc[1][0] = __builtin_amdgcn_mfma_f32_16x16x32_bf16(qf[1][ks], kf0, sacc[1][0], 0, 0, 0);
            sacc[1][1] = __builtin_amdgcn_mfma_f32_16x16x32_bf16(qf[1][ks], kf1, sacc[1][1], 0, 0, 0);
        }
        // masked + scaled scores to LDS
#pragma unroll
        for (int mt = 0; mt < 2; ++mt)
#pragma unroll
            for (int nt = 0; nt < 2; ++nt)
#pragma unroll
                for (int r = 0; r < 4; ++r) {
                    int row = m0w + mt * 16 + quad * 4 + r;
                    int col = n0w + nt * 16 + l15;
                    int i_abs = q0 + row, j_abs = j0 + col;
                    bool valid = (j_abs <= i_abs) && (i_abs - j_abs < 1024);
                    Ss[row][col] = valid ? sacc[mt][nt][r] * scale : -3.4e38f;
                }
        __syncthreads();

        // ---- online softmax: 4 consecutive lanes per row ----
        {
            float sv[16];
            float mx = -3.4e38f;
#pragma unroll
            for (int j = 0; j < 16; ++j) {
                sv[j] = Ss[srow_sm][scol_sm + j];
                mx = fmaxf(mx, sv[j]);
            }
            mx = fmaxf(mx, __shfl_xor(mx, 1));
            mx = fmaxf(mx, __shfl_xor(mx, 2));
            float m_new = fmaxf(m_i, mx);
            float alpha = expf(m_i - m_new);     // -3.4e38 - finite -> 0; 0 when stale
            float psum = 0.f;
#pragma unroll
            for (int j = 0; j < 16; ++j) {
                float p = (sv[j] > -1e30f) ? expf(sv[j] - m_new) : 0.f;
                Ps[srow_sm][scol_sm + j] = f2bf(p);
                psum += p;
            }
            psum += __shfl_xor(psum, 1);
            psum += __shfl_xor(psum, 2);
            l_i = l_i * alpha + psum;
            m_i = m_new;
            if ((tid & 3) == 0) alphas[srow_sm] = alpha;
        }
        __syncthreads();

        // ---- rescale O, then PV MFMA ----
#pragma unroll
        for (int mt = 0; mt < 2; ++mt)
#pragma unroll
            for (int r = 0; r < 4; ++r) {
                float al = alphas[m0w + mt * 16 + quad * 4 + r];
#pragma unroll
                for (int nt = 0; nt < 4; ++nt) oacc[mt][nt][r] *= al;
            }
#pragma unroll
        for (int ks = 0; ks < 2; ++ks) {
            bhalf8 pf0 = *reinterpret_cast<const bhalf8*>(&Ps[m0w + l15][ks * 32 + quad * 8]);
            bhalf8 pf1 = *reinterpret_cast<const bhalf8*>(&Ps[m0w + 16 + l15][ks * 32 + quad * 8]);
#pragma unroll
            for (int nt = 0; nt < 4; ++nt) {
                bhalf8 vf = *reinterpret_cast<const bhalf8*>(&Vs[n0v + nt * 16 + l15][ks * 32 + quad * 8]);
                oacc[0][nt] = __builtin_amdgcn_mfma_f32_16x16x32_bf16(pf0, vf, oacc[0][nt], 0, 0, 0);
                oacc[1][nt] = __builtin_amdgcn_mfma_f32_16x16x32_bf16(pf1, vf, oacc[1][nt], 0, 0, 0);
            }
        }
        __syncthreads();   // protect Ks/Vs re-staging
    }

    if ((tid & 3) == 0) lsum[srow_sm] = l_i;
    __syncthreads();
#pragma unroll
    for (int mt = 0; mt < 2; ++mt)
#pragma unroll
        for (int r = 0; r < 4; ++r) {
            int row = m0w + mt * 16 + quad * 4 + r;
            float inv = 1.0f / lsum[row];
#pragma unroll
            for (int nt = 0; nt < 4; ++nt)
                attn_out[qkbase + (long)row * 2048 + n0v + nt * 16 + l15] = oacc[mt][nt][r] * inv;
        }
}

// ---------------------------------------------------------------------------
// fq/fk/fv: silu (+affine for q/k) (+L2 norm over fd=512 for q/k) -> bf16
// ---------------------------------------------------------------------------
__global__ __launch_bounds__(128) void fqkv_kernel(
    const float* __restrict__ qkv, const float* __restrict__ qk_scale,
    const float* __restrict__ qk_offset, u16* __restrict__ out, int mode)
{
    int bid = blockIdx.x;
    int nh = bid & 3;
    int row = bid >> 2;
    const float* x = &qkv[(long)row * 6144 + mode * 2048 + nh * 512];
    __shared__ float red[128];
    float vals[4];
    float ss = 0.f;
#pragma unroll
    for (int ii = 0; ii < 4; ++ii) {
        int i = threadIdx.x + ii * 128;
        float v = x[i];
        float sg = 1.f / (1.f + expf(-v));
        float sv = v * sg;
        if (mode < 2) {
            int dcol = nh * 512 + i;
            sv = sv * qk_scale[dcol * 2 + mode] + qk_offset[dcol * 2 + mode];
        }
        vals[ii] = sv;
        ss += sv * sv;
    }
    float invn = 1.0f;
    if (mode < 2) {
        red[threadIdx.x] = ss; __syncthreads();
        for (int s_ = 64; s_ > 0; s_ >>= 1) {
            if (threadIdx.x < s_) red[threadIdx.x] += red[threadIdx.x + s_];
            __syncthreads();
        }
        invn = 1.0f / (sqrtf(red[0]) + 1e-12f);
    }
    u16* o = &out[(long)row * 2048 + nh * 512];
#pragma unroll
    for (int ii = 0; ii < 4; ++ii) o[threadIdx.x + ii * 128] = f2bf(vals[ii] * invn);
}

// ---------------------------------------------------------------------------
// fast-weight init: tile (4,512,512) x b=2 -> (8,512,512) fp32
// ---------------------------------------------------------------------------
__global__ void winit(const float* __restrict__ w0, const float* __restrict__ w1,
                      const float* __restrict__ w2, float* __restrict__ w0b,
                      float* __restrict__ w1b, float* __restrict__ w2b)
{
    long idx = (long)blockIdx.x * 256 + threadIdx.x;
    long src = ((idx >> 18) & 3) * 262144 + (idx & 262143);
    w0b[idx] = w0[src];
    w1b[idx] = w1[src];
    w2b[idx] = w2[src];
}

// ---------------------------------------------------------------------------
// scan elementwise 1 (fp32 temps in place; fv read as bf16)
// ---------------------------------------------------------------------------
__global__ void scan_ew1(const float* gate, const float* hpre, const float* dhb,
                         const u16* fvb, const float* lr, int c0,
                         float* T1, float* T2, float* T3, float* T4)
{
    long idx = (long)blockIdx.x * 256 + threadIdx.x;  // 8*1024*512
    int f = (int)(idx & 511);
    long r = idx >> 9;
    int ci = (int)(r & 1023);
    int z = (int)(r >> 10);
    int b_ = z >> 2, h = z & 3;
    long srow = (long)b_ * S + (long)c0 * CHUNK + ci;
    float g = gate[idx], hp = hpre[idx], dh = dhb[idx];
    float sg = 1.f / (1.f + expf(-g));
    float silu_g = g * sg;
    float hid = silu_g * hp;
    float dgate = dh * hp * (sg * (1.f + g * (1.f - sg)));
    float dhpre = dh * silu_g;
    float l0 = lr[srow * 12 + h];
    float l1 = lr[srow * 12 + 4 + h];
    float l2 = lr[srow * 12 + 8 + h];
    float fvv = bf2f(fvb[srow * 2048 + h * 512 + f]);
    T1[idx] = dgate * l0;
    T2[idx] = dhpre * l2;
    T3[idx] = fvv * l1;
    T4[idx] = hid;
}

// scan elementwise 2: T1 = silu(T1) * T2
__global__ void scan_ew2(float* T1, const float* T2)
{
    long idx = (long)blockIdx.x * 256 + threadIdx.x;
    float g = T1[idx];
    T1[idx] = g * (1.f / (1.f + expf(-g))) * T2[idx];
}

// ---------------------------------------------------------------------------
// ttt rmsnorm added into attn_out in place
// ---------------------------------------------------------------------------
__global__ __launch_bounds__(128) void ttt_norm_add(
    const float* __restrict__ ttt, const float* __restrict__ w, float* attnX)
{
    int bid = blockIdx.x;
    int h = bid & 3;
    int row = bid >> 2;
    const float* x = &ttt[(long)row * 2048 + h * 512];
    __shared__ float red[128];
    float v[4];
    float ss = 0.f;
#pragma unroll
    for (int ii = 0; ii < 4; ++ii) {
        v[ii] = x[threadIdx.x + ii * 128];
        ss += v[ii] * v[ii];
    }
    red[threadIdx.x] = ss; __syncthreads();
    for (int s_ = 64; s_ > 0; s_ >>= 1) {
        if (threadIdx.x < s_) red[threadIdx.x] += red[threadIdx.x + s_];
        __syncthreads();
    }
    float sc = rsqrtf(red[0] / 512.f + 1e-6f);
    float* o = &attnX[(long)row * 2048 + h * 512];
#pragma unroll
    for (int ii = 0; ii < 4; ++ii) {
        int i = threadIdx.x + ii * 128;
        o[i] = o[i] + v[ii] * sc * w[i];
    }
}

// ---------------------------------------------------------------------------
extern "C" void kernel_launch(void* const* d_in, const int* in_sizes, int n_in,
                              void* d_out, int out_size, void* d_ws, size_t ws_size,
                              hipStream_t stream)
{
    const float* hs        = (const float*)d_in[0];
    const float* Wqkv      = (const float*)d_in[1];
    const float* Wo        = (const float*)d_in[2];
    const float* q_norm_w  = (const float*)d_in[3];
    const float* k_norm_w  = (const float*)d_in[4];
    const float* w0        = (const float*)d_in[5];
    const float* w1        = (const float*)d_in[6];
    const float* w2        = (const float*)d_in[7];
    const float* lr_w      = (const float*)d_in[8];
    const float* lr_b      = (const float*)d_in[9];
    const float* qk_scale  = (const float*)d_in[10];
    const float* qk_offset = (const float*)d_in[11];
    const float* ttt_w     = (const float*)d_in[12];
    float* out = (float*)d_out;
    float* ws = (float*)d_ws;

    // ---- workspace (fp32 units), total 65,060,864 floats = 248.2 MiB -------
    const long F_QKV = 0;          // qkv fp32 (25,165,824); later:
    const long F_TTT = 0;          //   ttt fp32 (8,388,608)
    const long F_T1  = 8388608;    //   T1..T4 fp32 (4 x 4,194,304)
    const long F_T2  = 12582912;
    const long F_T3  = 16777216;
    const long F_T4  = 20971520;
    const long F_AQ  = 25165824;   // hs_b -> aq bf16 (4M fl) + vt bf16 (4M fl) -> fq_b | fk_b
    const long F_AK  = 33554432;   // Wqkv_b -> ak bf16 -> fv_b | hq_b | fkt
    const long F_ATT = 41943040;   // attX fp32 (8,388,608)
    const long F_TTa = 50331648;   // transposed bf16 temp A (2,097,152)
    const long F_TTb = 52428800;   // transposed bf16 temp B (2,097,152)
    const long F_W0  = 54525952;   // weights fp32 (3 x 2,097,152)
    const long F_W1  = 56623104;
    const long F_W2  = 58720256;
    const long F_W0B = 60817408;   // bf16 snapshots (4 x 1,048,576)
    const long F_W1B = 61865984;
    const long F_W2B = 62914560;
    const long F_W1T = 63963136;
    const long F_LR  = 65011712;   // end 65,060,864

    u16* hs_b   = (u16*)(ws + F_AQ);
    u16* wqkv_b = (u16*)(ws + F_AK);
    u16* aq_b   = (u16*)(ws + F_AQ);             // bf16, 8,388,608 elems = 4,194,304 floats
    u16* ak_b   = (u16*)(ws + F_AK);             // bf16, 8,388,608 elems = 4,194,304 floats
    u16* vt_b   = (u16*)(ws + F_AQ + 4194304);   // bf16, 8,388,608 elems; ends exactly at F_AK
    u16* fq_b   = (u16*)(ws + F_AQ);
    u16* fk_b   = (u16*)(ws + F_AQ + 4194304);
    u16* fv_b   = (u16*)(ws + F_AK);
    u16* hq_b   = (u16*)(ws + F_AK + 4194304);
    u16* fkt_b  = (u16*)(ws + F_AK + 6291456);
    u16* tta    = (u16*)(ws + F_TTa);
    u16* ttb    = (u16*)(ws + F_TTb);
    u16* w0b_u  = (u16*)(ws + F_W0B);
    u16* w1b_u  = (u16*)(ws + F_W1B);
    u16* w2b_u  = (u16*)(ws + F_W2B);
    u16* w1t_u  = (u16*)(ws + F_W1T);
    u16* x_b    = (u16*)(ws + F_T1);   // after scan
    u16* wo_b   = (u16*)(ws + F_T3);   // after scan

    // 1. qkv = hs @ Wqkv^T  (bf16 MFMA)
    cvt_bf16<<<8192, 256, 0, stream>>>(hs, hs_b, 8388608);
    cvt_bf16<<<12288, 256, 0, stream>>>(Wqkv, wqkv_b, 12582912);
    gemm_mfma<<<dim3(48, 32, 1), 256, 0, stream>>>(
        hs_b, 2048, 0, 0, wqkv_b, 2048, 0, 0, ws + F_QKV, 6144, 0, 0, 2048, 0);
    // 2. lr
    lr_kernel<<<4096, 256, 0, stream>>>(hs, lr_w, lr_b, ws + F_LR);
    // 3. rmsnorm + rope -> bf16 (overwrites hs_b / wqkv_b — they are dead)
    rmsnorm_rope<<<4096, 256, 0, stream>>>(ws + F_QKV, 0,    q_norm_w, aq_b);
    rmsnorm_rope<<<4096, 256, 0, stream>>>(ws + F_QKV, 2048, k_norm_w, ak_b);
    // 3b. V transpose for attention
    vt_prep<<<dim3(32, 2, 32), 256, 0, stream>>>(ws + F_QKV, vt_b);
    // 4. attention (bf16 MFMA)
    attn_mfma<<<dim3(32, 16, 2), 256, 0, stream>>>(aq_b, ak_b, vt_b, ws + F_ATT);
    // 5. fq/fk/fv bf16 (overwrite aq/vt/ak regions — dead after attention)
    fqkv_kernel<<<16384, 128, 0, stream>>>(ws + F_QKV, qk_scale, qk_offset, fq_b, 0);
    fqkv_kernel<<<16384, 128, 0, stream>>>(ws + F_QKV, qk_scale, qk_offset, fk_b, 1);
    fqkv_kernel<<<16384, 128, 0, stream>>>(ws + F_QKV, qk_scale, qk_offset, fv_b, 2);
    // 6. fast-weight init (fp32 masters)
    winit<<<8192, 256, 0, stream>>>(w0, w1, w2, ws + F_W0, ws + F_W1, ws + F_W2);

    for (int c0 = 0; c0 < 2; ++c0) {
        const long cOff = (long)c0 * 2097152;           // chunk offset in bf16 elems
        // bf16 snapshots of weights + w1^T
        cvt_bf16<<<2048, 256, 0, stream>>>(ws + F_W0, w0b_u, 2097152);
        cvt_bf16<<<2048, 256, 0, stream>>>(ws + F_W2, w2b_u, 2097152);
        transpose_cvt<float><<<dim3(8, 8, 8), 256, 0, stream>>>(
            ws + F_W1, 512, 1048576, 262144, w1t_u, 512, 1048576, 262144);
        // fk^T for the updates
        transpose_cvt<u16><<<dim3(8, 16, 8), 256, 0, stream>>>(
            fk_b + cOff, 2048, 4194304, 512, fkt_b, 1024, 2097152, 524288);
        // gate / hpre / dh
        gemm_mfma<<<dim3(4, 8, 8), 256, 0, stream>>>(
            fk_b + cOff, 2048, 4194304, 512, w0b_u, 512, 1048576, 262144,
            ws + F_T1, 512, 2097152, 524288, 512, 0);
        gemm_mfma<<<dim3(4, 8, 8), 256, 0, stream>>>(
            fk_b + cOff, 2048, 4194304, 512, w2b_u, 512, 1048576, 262144,
            ws + F_T2, 512, 2097152, 524288, 512, 0);
        gemm_mfma<<<dim3(4, 8, 8), 256, 0, stream>>>(
            fv_b + cOff, 2048, 4194304, 512, w1t_u, 512, 1048576, 262144,
            ws + F_T3, 512, 2097152, 524288, 512, 0);
        // elementwise
        scan_ew1<<<16384, 256, 0, stream>>>(ws + F_T1, ws + F_T2, ws + F_T3,
                                            fv_b, ws + F_LR, c0,
                                            ws + F_T1, ws + F_T2, ws + F_T3, ws + F_T4);
        // w0 / w2 updates: transpose T1,T2 then C += A^T-form MFMA
        transpose_cvt<float><<<dim3(8, 16, 8), 256, 0, stream>>>(
            ws + F_T1, 512, 2097152, 524288, tta, 1024, 2097152, 524288);
        transpose_cvt<float><<<dim3(8, 16, 8), 256, 0, stream>>>(
            ws + F_T2, 512, 2097152, 524288, ttb, 1024, 2097152, 524288);
        gemm_mfma<<<dim3(4, 4, 8), 256, 0, stream>>>(
            tta, 1024, 2097152, 524288, fkt_b, 1024, 2097152, 524288,
            ws + F_W0, 512, 1048576, 262144, 1024, 1);
        gemm_mfma<<<dim3(4, 4, 8), 256, 0, stream>>>(
            ttb, 1024, 2097152, 524288, fkt_b, 1024, 2097152, 524288,
            ws + F_W2, 512, 1048576, 262144, 1024, 1);
        // w1 update: transpose T3,T4
        transpose_cvt<float><<<dim3(8, 16, 8), 256, 0, stream>>>(
            ws + F_T3, 512, 2097152, 524288, tta, 1024, 2097152, 524288);
        transpose_cvt<float><<<dim3(8, 16, 8), 256, 0, stream>>>(
            ws + F_T4, 512, 2097152, 524288, ttb, 1024, 2097152, 524288);
        gemm_mfma<<<dim3(4, 4, 8), 256, 0, stream>>>(
            tta, 1024, 2097152, 524288, ttb, 1024, 2097152, 524288,
            ws + F_W1, 512, 1048576, 262144, 1024, 1);
        // query pass with updated weights
        cvt_bf16<<<2048, 256, 0, stream>>>(ws + F_W0, w0b_u, 2097152);
        cvt_bf16<<<2048, 256, 0, stream>>>(ws + F_W2, w2b_u, 2097152);
        cvt_bf16<<<2048, 256, 0, stream>>>(ws + F_W1, w1b_u, 2097152);
        gemm_mfma<<<dim3(4, 8, 8), 256, 0, stream>>>(
            fq_b + cOff, 2048, 4194304, 512, w0b_u, 512, 1048576, 262144,
            ws + F_T1, 512, 2097152, 524288, 512, 0);
        gemm_mfma<<<dim3(4, 8, 8), 256, 0, stream>>>(
            fq_b + cOff, 2048, 4194304, 512, w2b_u, 512, 1048576, 262144,
            ws + F_T2, 512, 2097152, 524288, 512, 0);
        scan_ew2<<<16384, 256, 0, stream>>>(ws + F_T1, ws + F_T2);
        cvt_bf16<<<4096, 256, 0, stream>>>(ws + F_T1, hq_b, 4194304);
        // oi = hq @ w1^T -> ttt (strided (b,s,NH,fd))
        gemm_mfma<<<dim3(4, 8, 8), 256, 0, stream>>>(
            hq_b, 512, 2097152, 524288, w1b_u, 512, 1048576, 262144,
            ws + F_TTT + cOff, 2048, 4194304, 512, 512, 0);
    }

    // 8. ttt rmsnorm + add into attX
    ttt_norm_add<<<16384, 128, 0, stream>>>(ws + F_TTT, ttt_w, ws + F_ATT);
    // 9. out = X @ Wo^T  (bf16 MFMA; X_b/Wo_b reuse dead T region)
    cvt_bf16<<<8192, 256, 0, stream>>>(ws + F_ATT, x_b, 8388608);
    cvt_bf16<<<4096, 256, 0, stream>>>(Wo, wo_b, 4194304);
    gemm_mfma<<<dim3(16, 32, 1), 256, 0, stream>>>(
        x_b, 2048, 0, 0, wo_b, 2048, 0, 0, out, 2048, 0, 0, 2048, 0);
}

// Round 6
// 1006.826 us; speedup vs baseline: 1.9859x; 1.1517x over previous
//
#include <hip/hip_runtime.h>
#include <hip/hip_bf16.h>
#include <math.h>

#define S 2048
#define NH 4
#define FD 512
#define CHUNK 1024
#define BASE_LR_INV -6.9072552373f

typedef unsigned short u16;
typedef unsigned int u32;
typedef short bhalf8 __attribute__((ext_vector_type(8)));   // 8 bf16 = 4 VGPRs
typedef float floatx4 __attribute__((ext_vector_type(4)));

__device__ __forceinline__ u16 f2bf(float f) {               // RNE fp32->bf16
    u32 x = __float_as_uint(f);
    return (u16)((x + 0x7FFFu + ((x >> 16) & 1u)) >> 16);
}
__device__ __forceinline__ float bf2f(u16 u) {
    return __uint_as_float(((u32)u) << 16);
}
__device__ __forceinline__ float ldval(const float* p) { return *p; }
__device__ __forceinline__ float ldval(const u16* p) { return bf2f(*p); }

// async global->LDS, 16B per lane. LDS dest must be wave-uniform base
// (HW writes base + lane*16); global src is per-lane.
__device__ __forceinline__ void gl_lds16(const u16* g, u16* l)
{
    __builtin_amdgcn_global_load_lds(
        (const __attribute__((address_space(1))) void*)g,
        (__attribute__((address_space(3))) void*)l, 16, 0, 0);
}

// ---------------------------------------------------------------------------
// bf16 MFMA GEMM:  C(fp32) = A @ B^T, A:(M,K) bf16 lda, B:(N,K) bf16 ldb.
// 128x128 block tile, 256 thr = 4 waves (2x2 of 64x64), BK=32, double-buffered
// LDS with global_load_lds prefetch. acc_flag: C += result.
// Batched: ptr += (z>>2)*offO + (z&3)*offI.  M,N mult of 128; K mult of 64.
// ---------------------------------------------------------------------------
__global__ __launch_bounds__(256) void gemm_mfma(
    const u16* __restrict__ A, int lda, long offAo, long offAi,
    const u16* __restrict__ B, int ldb, long offBo, long offBi,
    float* __restrict__ C, int ldc, long offCo, long offCi, int K, int acc_flag)
{
    int z = blockIdx.z;
    A += (long)(z >> 2) * offAo + (long)(z & 3) * offAi;
    B += (long)(z >> 2) * offBo + (long)(z & 3) * offBi;
    C += (long)(z >> 2) * offCo + (long)(z & 3) * offCi;
    __shared__ u16 As0[128][32], Bs0[128][32];   // linear: required by global_load_lds
    __shared__ u16 As1[128][32], Bs1[128][32];
    const int tid = threadIdx.x;
    const int wid = tid >> 6, lane = tid & 63;
    const int quad = lane >> 4, l15 = lane & 15;
    const int m0w = (wid >> 1) * 64, n0w = (wid & 1) * 64;
    const int row0 = blockIdx.y * 128, col0 = blockIdx.x * 128;
    // staging lane map: chunk = 16 rows x 32 cols (1 KiB); lane l -> row l>>2, col (l&3)*8
    const int srow = lane >> 2, scol = (lane & 3) * 8;
    const int ca = wid * 16, cb = (wid + 4) * 16;   // this wave's two chunk rows

    const u16* gA0 = &A[(long)(row0 + ca + srow) * lda + scol];
    const u16* gA1 = &A[(long)(row0 + cb + srow) * lda + scol];
    const u16* gB0 = &B[(long)(col0 + ca + srow) * ldb + scol];
    const u16* gB1 = &B[(long)(col0 + cb + srow) * ldb + scol];

    floatx4 acc[4][4];
#pragma unroll
    for (int a = 0; a < 4; ++a)
#pragma unroll
        for (int b = 0; b < 4; ++b) acc[a][b] = {0.f, 0.f, 0.f, 0.f};

#define GSTAGE(AS, BS, kk) do { \
    gl_lds16(gA0 + (kk), &AS[ca][0]); \
    gl_lds16(gA1 + (kk), &AS[cb][0]); \
    gl_lds16(gB0 + (kk), &BS[ca][0]); \
    gl_lds16(gB1 + (kk), &BS[cb][0]); } while (0)

#define GCOMP(AS, BS) do { \
    bhalf8 af[4], bf[4]; \
    _Pragma("unroll") \
    for (int mt = 0; mt < 4; ++mt) \
        af[mt] = *reinterpret_cast<const bhalf8*>(&AS[m0w + mt * 16 + l15][quad * 8]); \
    _Pragma("unroll") \
    for (int nt = 0; nt < 4; ++nt) \
        bf[nt] = *reinterpret_cast<const bhalf8*>(&BS[n0w + nt * 16 + l15][quad * 8]); \
    _Pragma("unroll") \
    for (int mt = 0; mt < 4; ++mt) \
        _Pragma("unroll") \
        for (int nt = 0; nt < 4; ++nt) \
            acc[mt][nt] = __builtin_amdgcn_mfma_f32_16x16x32_bf16( \
                af[mt], bf[nt], acc[mt][nt], 0, 0, 0); } while (0)

    const int nt = K >> 5;          // even: K % 64 == 0
    GSTAGE(As0, Bs0, 0);
    for (int t = 0; t < nt; t += 2) {
        __syncthreads();
        GSTAGE(As1, Bs1, (t + 1) * 32);   // prefetch flies under compute
        GCOMP(As0, Bs0);
        __syncthreads();
        if (t + 2 < nt) GSTAGE(As0, Bs0, (t + 2) * 32);
        GCOMP(As1, Bs1);
    }
#undef GSTAGE
#undef GCOMP

#pragma unroll
    for (int mt = 0; mt < 4; ++mt)
#pragma unroll
        for (int nt = 0; nt < 4; ++nt) {
            int col = col0 + n0w + nt * 16 + l15;
#pragma unroll
            for (int r = 0; r < 4; ++r) {
                int row = row0 + m0w + mt * 16 + quad * 4 + r;
                long off = (long)row * ldc + col;
                float v = acc[mt][nt][r];
                C[off] = acc_flag ? (C[off] + v) : v;
            }
        }
}

// ---------------------------------------------------------------------------
// 64x64-tile variant for small GEMMs (M,N mult of 64; K mult of 64).
// 4 waves, each a 32x32 quadrant; dbuf + global_load_lds. 4x the blocks of
// the 128-tile version -> occupancy for 512x512-class problems.
// ---------------------------------------------------------------------------
__global__ __launch_bounds__(256) void gemm_mfma64(
    const u16* __restrict__ A, int lda, long offAo, long offAi,
    const u16* __restrict__ B, int ldb, long offBo, long offBi,
    float* __restrict__ C, int ldc, long offCo, long offCi, int K, int acc_flag)
{
    int z = blockIdx.z;
    A += (long)(z >> 2) * offAo + (long)(z & 3) * offAi;
    B += (long)(z >> 2) * offBo + (long)(z & 3) * offBi;
    C += (long)(z >> 2) * offCo + (long)(z & 3) * offCi;
    __shared__ u16 As0[64][32], Bs0[64][32];
    __shared__ u16 As1[64][32], Bs1[64][32];
    const int tid = threadIdx.x;
    const int wid = tid >> 6, lane = tid & 63;
    const int quad = lane >> 4, l15 = lane & 15;
    const int m0w = (wid >> 1) * 32, n0w = (wid & 1) * 32;
    const int row0 = blockIdx.y * 64, col0 = blockIdx.x * 64;
    const int srow = lane >> 2, scol = (lane & 3) * 8;
    const int ca = wid * 16;          // wave's chunk row (4 x 16 = 64)

    const u16* gA0 = &A[(long)(row0 + ca + srow) * lda + scol];
    const u16* gB0 = &B[(long)(col0 + ca + srow) * ldb + scol];

    floatx4 acc[2][2];
#pragma unroll
    for (int a = 0; a < 2; ++a)
#pragma unroll
        for (int b = 0; b < 2; ++b) acc[a][b] = {0.f, 0.f, 0.f, 0.f};

#define GSTAGE64(AS, BS, kk) do { \
    gl_lds16(gA0 + (kk), &AS[ca][0]); \
    gl_lds16(gB0 + (kk), &BS[ca][0]); } while (0)

#define GCOMP64(AS, BS) do { \
    bhalf8 af[2], bf[2]; \
    _Pragma("unroll") \
    for (int mt = 0; mt < 2; ++mt) \
        af[mt] = *reinterpret_cast<const bhalf8*>(&AS[m0w + mt * 16 + l15][quad * 8]); \
    _Pragma("unroll") \
    for (int nt = 0; nt < 2; ++nt) \
        bf[nt] = *reinterpret_cast<const bhalf8*>(&BS[n0w + nt * 16 + l15][quad * 8]); \
    _Pragma("unroll") \
    for (int mt = 0; mt < 2; ++mt) \
        _Pragma("unroll") \
        for (int nt = 0; nt < 2; ++nt) \
            acc[mt][nt] = __builtin_amdgcn_mfma_f32_16x16x32_bf16( \
                af[mt], bf[nt], acc[mt][nt], 0, 0, 0); } while (0)

    const int nt = K >> 5;          // even
    GSTAGE64(As0, Bs0, 0);
    for (int t = 0; t < nt; t += 2) {
        __syncthreads();
        GSTAGE64(As1, Bs1, (t + 1) * 32);
        GCOMP64(As0, Bs0);
        __syncthreads();
        if (t + 2 < nt) GSTAGE64(As0, Bs0, (t + 2) * 32);
        GCOMP64(As1, Bs1);
    }
#undef GSTAGE64
#undef GCOMP64

#pragma unroll
    for (int mt = 0; mt < 2; ++mt)
#pragma unroll
        for (int nt = 0; nt < 2; ++nt) {
            int col = col0 + n0w + nt * 16 + l15;
#pragma unroll
            for (int r = 0; r < 4; ++r) {
                int row = row0 + m0w + mt * 16 + quad * 4 + r;
                long off = (long)row * ldc + col;
                float v = acc[mt][nt][r];
                C[off] = acc_flag ? (C[off] + v) : v;
            }
        }
}

// ---------------------------------------------------------------------------
// flat fp32 -> bf16 convert (n mult of 4)
// ---------------------------------------------------------------------------
__global__ __launch_bounds__(256) void cvt_bf16(
    const float* __restrict__ in, u16* __restrict__ out, long n)
{
    long i = ((long)blockIdx.x * 256 + threadIdx.x) * 4;
    if (i >= n) return;
    float4 v = *reinterpret_cast<const float4*>(&in[i]);
    ushort4 o;
    o.x = f2bf(v.x); o.y = f2bf(v.y); o.z = f2bf(v.z); o.w = f2bf(v.w);
    *reinterpret_cast<ushort4*>(&out[i]) = o;
}

// ---------------------------------------------------------------------------
// pack master (8,512,512) fp32 -> (8,1024,512) bf16 rows [half*512, half*512+512)
// ---------------------------------------------------------------------------
__global__ __launch_bounds__(256) void cvt_pack(
    const float* __restrict__ in, u16* __restrict__ out, int half)
{
    long idx = ((long)blockIdx.x * 256 + threadIdx.x) * 4;   // over 2,097,152
    int col = (int)(idx & 511);
    long r = idx >> 9;
    int row = (int)(r & 511);
    int z = (int)(r >> 9);
    float4 v = *reinterpret_cast<const float4*>(&in[idx]);
    ushort4 o;
    o.x = f2bf(v.x); o.y = f2bf(v.y); o.z = f2bf(v.z); o.w = f2bf(v.w);
    long dst = ((long)z * 1024 + half * 512 + row) * 512 + col;
    *reinterpret_cast<ushort4*>(&out[dst]) = o;
}

// ---------------------------------------------------------------------------
// batched transpose + cvt: in[z] (R,C) ld=ldin  ->  out[z] (C,R) bf16 ld=ldout
// grid (C/64, R/64, 8)
// ---------------------------------------------------------------------------
template <typename TIN>
__global__ __launch_bounds__(256) void transpose_cvt(
    const TIN* __restrict__ in, int ldin, long inOo, long inOi,
    u16* __restrict__ out, int ldout, long outOo, long outOi)
{
    int z = blockIdx.z;
    in  += (long)(z >> 2) * inOo + (long)(z & 3) * inOi;
    out += (long)(z >> 2) * outOo + (long)(z & 3) * outOi;
    int r0 = blockIdx.y * 64, c0 = blockIdx.x * 64;
    __shared__ float t[64][65];
    for (int i = threadIdx.x; i < 4096; i += 256) {
        int r = i >> 6, c = i & 63;
        t[r][c] = ldval(&in[(long)(r0 + r) * ldin + c0 + c]);
    }
    __syncthreads();
    for (int i = threadIdx.x; i < 4096; i += 256) {
        int r = i >> 6, c = i & 63;
        out[(long)(c0 + r) * ldout + r0 + c] = f2bf(t[c][r]);
    }
}

// ---------------------------------------------------------------------------
// paired transpose + cvt: two (R=1024, C=512) fp32 sources -> two bf16 dests
// (C,R)=(512,1024) ld=ldout. grid (8, 16, 16); z>=8 selects pair B.
// ---------------------------------------------------------------------------
__global__ __launch_bounds__(256) void transpose_cvt2(
    const float* __restrict__ inA, const float* __restrict__ inB, int ldin, long inOi,
    u16* __restrict__ outA, u16* __restrict__ outB, int ldout, long outOi)
{
    int zz = blockIdx.z;
    int z = zz & 7, sel = zz >> 3;
    const float* in = (sel ? inB : inA) + (long)z * inOi;
    u16* out = (sel ? outB : outA) + (long)z * outOi;
    int r0 = blockIdx.y * 64, c0 = blockIdx.x * 64;
    __shared__ float t[64][65];
    for (int i = threadIdx.x; i < 4096; i += 256) {
        int r = i >> 6, c = i & 63;
        t[r][c] = in[(long)(r0 + r) * ldin + c0 + c];
    }
    __syncthreads();
    for (int i = threadIdx.x; i < 4096; i += 256) {
        int r = i >> 6, c = i & 63;
        out[(long)(c0 + r) * ldout + r0 + c] = f2bf(t[c][r]);
    }
}

// ---------------------------------------------------------------------------
// V transpose for attention: qkv V slice (b,s,h,128) fp32 -> vt (b,h,128,s) bf16
// grid (S/64, 128/64, b*16)
// ---------------------------------------------------------------------------
__global__ __launch_bounds__(256) void vt_prep(
    const float* __restrict__ qkv, u16* __restrict__ vt)
{
    int z = blockIdx.z;          // b*16 + h
    int b_ = z >> 4, h = z & 15;
    int s0 = blockIdx.x * 64, d0 = blockIdx.y * 64;
    __shared__ float t[64][65];
    const float* src = &qkv[(long)(b_ * S) * 6144 + 4096 + h * 128 + d0];
    for (int i = threadIdx.x; i < 4096; i += 256) {
        int r = i >> 6, c = i & 63;      // r: s, c: d
        t[r][c] = src[(long)(s0 + r) * 6144 + c];
    }
    __syncthreads();
    u16* dst = &vt[((long)z * 128 + d0) * 2048 + s0];
    for (int i = threadIdx.x; i < 4096; i += 256) {
        int r = i >> 6, c = i & 63;      // r: d, c: s
        dst[(long)r * 2048 + c] = f2bf(t[c][r]);
    }
}

// ---------------------------------------------------------------------------
// lr = softplus(hs @ lr_w^T + lr_b + BASE_LR_INV)  -> (4096, 12)
// one wave per output j (striped); shuffle reduce, single barrier
// ---------------------------------------------------------------------------
__global__ __launch_bounds__(256) void lr_kernel(
    const float* __restrict__ hs, const float* __restrict__ lr_w,
    const float* __restrict__ lr_b, float* __restrict__ lr)
{
    int row = blockIdx.x;
    __shared__ float hrow[2048];
    for (int i = threadIdx.x; i < 2048; i += 256) hrow[i] = hs[(long)row * 2048 + i];
    __syncthreads();
    int wid = threadIdx.x >> 6, lane = threadIdx.x & 63;
    for (int j = wid; j < 12; j += 4) {
        const float* wrow = &lr_w[(long)j * 2048];
        float ss = 0.f;
        for (int i = lane; i < 2048; i += 64) ss += hrow[i] * wrow[i];
#pragma unroll
        for (int off = 32; off > 0; off >>= 1) ss += __shfl_down(ss, off);
        if (lane == 0) {
            float x = ss + lr_b[j] + BASE_LR_INV;
            lr[(long)row * 12 + j] = (x > 20.f) ? x : log1pf(expf(x));
        }
    }
}

// ---------------------------------------------------------------------------
// rmsnorm over d=2048 + RoPE per head (hd=128) -> packed bf16 (b,s,16,128)
// trig hoisted: only 64 distinct (si,t2) pairs per row -> LDS table
// ---------------------------------------------------------------------------
__global__ __launch_bounds__(256) void rmsnorm_rope(
    const float* __restrict__ qkv, int colOff, const float* __restrict__ w,
    u16* __restrict__ out)
{
    int row = blockIdx.x;            // b*s
    int si = row & (S - 1);
    const float* x = &qkv[(long)row * 6144 + colOff];
    __shared__ float xn[2048];
    __shared__ float red[256];
    __shared__ float cst[64], snt[64];
    if (threadIdx.x < 64) {
        float inv_freq = powf(500000.0f, -(float)threadIdx.x / 64.0f);
        float ang = (float)si * inv_freq;
        float sn, cs;
        sincosf(ang, &sn, &cs);
        cst[threadIdx.x] = cs;
        snt[threadIdx.x] = sn;
    }
    float ss = 0.f;
    for (int i = threadIdx.x; i < 2048; i += 256) { float v = x[i]; ss += v * v; }
    red[threadIdx.x] = ss; __syncthreads();
    for (int s_ = 128; s_ > 0; s_ >>= 1) {
        if (threadIdx.x < s_) red[threadIdx.x] += red[threadIdx.x + s_];
        __syncthreads();
    }
    float scale = rsqrtf(red[0] / 2048.f + 1e-6f);
    for (int i = threadIdx.x; i < 2048; i += 256) xn[i] = x[i] * scale * w[i];
    __syncthreads();
    for (int i = threadIdx.x; i < 2048; i += 256) {
        int tt = i & 127;
        int t2 = tt & 63;
        float cs = cst[t2], sn = snt[t2];
        float v;
        if (tt < 64) v = xn[i] * cs - xn[i + 64] * sn;
        else         v = xn[i] * cs + xn[i - 64] * sn;
        out[(long)row * 2048 + i] = f2bf(v);
    }
}

// ---------------------------------------------------------------------------
// Flash-style sliding-window causal attention, bf16 MFMA.
// Block: 64 q-rows x one head; 256 thr = 4 waves.
// ---------------------------------------------------------------------------
__global__ __launch_bounds__(256) void attn_mfma(
    const u16* __restrict__ aq, const u16* __restrict__ ak,
    const u16* __restrict__ vt, float* __restrict__ attn_out)
{
    const int qt = blockIdx.x;   // 0..31
    const int h  = blockIdx.y;   // 0..15
    const int b_ = blockIdx.z;   // 0..1
    const int q0 = qt * 64;
    const int tid = threadIdx.x;
    const int wid = tid >> 6, lane = tid & 63;
    const int quad = lane >> 4, l15 = lane & 15;
    const int m0w = (wid >> 1) * 32;      // q rows for this wave
    const int n0w = (wid & 1) * 32;       // kv cols (QK phase)
    const int n0v = (wid & 1) * 64;       // d cols (PV phase)
    const float scale = 0.088388347648318447f;

    __shared__ u16  Ks[64][136];   // K tile (also Q staging); 272B rows, 16B aligned
    __shared__ float Ss[64][67];   // scores; pad 67 -> conflict-free softmax reads
    __shared__ u16  Ps[64][72];    // P bf16; 144B rows
    __shared__ u16  Vs[128][72];   // V^T tile: [d][kv]
    __shared__ float alphas[64];
    __shared__ float lsum[64];

    const long qkbase = (long)(b_ * S + q0) * 2048 + h * 128;
    const long vtbase = ((long)(b_ * 16 + h)) * 128 * 2048;

    // ---- stage Q tile into Ks, hoist Q fragments into registers ----
    {
        int r = tid >> 2, c = (tid & 3) * 32;
        const u16* g = &aq[qkbase + (long)r * 2048 + c];
#pragma unroll
        for (int o = 0; o < 32; o += 8)
            *reinterpret_cast<uint4*>(&Ks[r][c + o]) = *reinterpret_cast<const uint4*>(g + o);
    }
    __syncthreads();
    bhalf8 qf[2][4];
#pragma unroll
    for (int mt = 0; mt < 2; ++mt)
#pragma unroll
        for (int ks = 0; ks < 4; ++ks)
            qf[mt][ks] = *reinterpret_cast<const bhalf8*>(&Ks[m0w + mt * 16 + l15][ks * 32 + quad * 8]);
    __syncthreads();

    floatx4 oacc[2][4];
#pragma unroll
    for (int mt = 0; mt < 2; ++mt)
#pragma unroll
        for (int nt = 0; nt < 4; ++nt) oacc[mt][nt] = {0.f, 0.f, 0.f, 0.f};
    float m_i = -3.4e38f, l_i = 0.f;           // row = tid>>2 (4 threads replicate)
    const int srow_sm = tid >> 2, scol_sm = (tid & 3) * 16;

    const int st = (qt >= 16) ? (qt - 16) : 0;
    for (int kt = st; kt <= qt; ++kt) {
        const int j0 = kt * 64;
        // stage K tile (64 x 128 bf16)
        {
            int r = tid >> 2, c = (tid & 3) * 32;
            const u16* g = &ak[(long)(b_ * S + j0) * 2048 + h * 128 + (long)r * 2048 + c];
#pragma unroll
            for (int o = 0; o < 32; o += 8)
                *reinterpret_cast<uint4*>(&Ks[r][c + o]) = *reinterpret_cast<const uint4*>(g + o);
        }
        // stage V^T tile (128 d-rows x 64 kv-cols bf16)
        {
            int r = tid >> 1, c = (tid & 1) * 32;
            const u16* g = &vt[vtbase + (long)r * 2048 + j0 + c];
#pragma unroll
            for (int o = 0; o < 32; o += 8)
                *reinterpret_cast<uint4*>(&Vs[r][c + o]) = *reinterpret_cast<const uint4*>(g + o);
        }
        __syncthreads();

        // ---- QK^T: 32x32 quadrant per wave ----
        floatx4 sacc[2][2];
#pragma unroll
        for (int mt = 0; mt < 2; ++mt)
#pragma unroll
            for (int nt = 0; nt < 2; ++nt) sacc[mt][nt] = {0.f, 0.f, 0.f, 0.f};
#pragma unroll
        for (int ks = 0; ks < 4; ++ks) {
            bhalf8 kf0 = *reinterpret_cast<const bhalf8*>(&Ks[n0w + l15][ks * 32 + quad * 8]);
            bhalf8 kf1 = *reinterpret_cast<const bhalf8*>(&Ks[n0w + 16 + l15][ks * 32 + quad * 8]);
            sacc[0][0] = __builtin_amdgcn_mfma_f32_16x16x32_bf16(qf[0][ks], kf0, sacc[0][0], 0, 0, 0);
            sacc[0][1] = __builtin_amdgcn_mfma_f32_16x16x32_bf16(qf[0][ks], kf1, sacc[0][1], 0, 0, 0);
            sacc[1][0] = __builtin_amdgcn_mfma_f32_16x16x32_bf16(qf[1][ks], kf0, sacc[1][0], 0, 0, 0);
            sacc[1][1] = __builtin_amdgcn_mfma_f32_16x16x32_bf16(qf[1][ks], kf1, sacc[1][1], 0, 0, 0);
        }
        // masked + scaled scores to LDS
#pragma unroll
        for (int mt = 0; mt < 2; ++mt)
#pragma unroll
            for (int nt = 0; nt < 2; ++nt)
#pragma unroll
                for (int r = 0; r < 4; ++r) {
                    int row = m0w + mt * 16 + quad * 4 + r;
                    int col = n0w + nt * 16 + l15;
                    int i_abs = q0 + row, j_abs = j0 + col;
                    bool valid = (j_abs <= i_abs) && (i_abs - j_abs < 1024);
                    Ss[row][col] = valid ? sacc[mt][nt][r] * scale : -3.4e38f;
                }
        __syncthreads();

        // ---- online softmax: 4 consecutive lanes per row ----
        {
            float sv[16];
            float mx = -3.4e38f;
#pragma unroll
            for (int j = 0; j < 16; ++j) {
                sv[j] = Ss[srow_sm][scol_sm + j];
                mx = fmaxf(mx, sv[j]);
            }
            mx = fmaxf(mx, __shfl_xor(mx, 1));
            mx = fmaxf(mx, __shfl_xor(mx, 2));
            float m_new = fmaxf(m_i, mx);
            float alpha = expf(m_i - m_new);
            float psum = 0.f;
#pragma unroll
            for (int j = 0; j < 16; ++j) {
                float p = (sv[j] > -1e30f) ? expf(sv[j] - m_new) : 0.f;
                Ps[srow_sm][scol_sm + j] = f2bf(p);
                psum += p;
            }
            psum += __shfl_xor(psum, 1);
            psum += __shfl_xor(psum, 2);
            l_i = l_i * alpha + psum;
            m_i = m_new;
            if ((tid & 3) == 0) alphas[srow_sm] = alpha;
        }
        __syncthreads();

        // ---- rescale O, then PV MFMA ----
#pragma unroll
        for (int mt = 0; mt < 2; ++mt)
#pragma unroll
            for (int r = 0; r < 4; ++r) {
                float al = alphas[m0w + mt * 16 + quad * 4 + r];
#pragma unroll
                for (int nt = 0; nt < 4; ++nt) oacc[mt][nt][r] *= al;
            }
#pragma unroll
        for (int ks = 0; ks < 2; ++ks) {
            bhalf8 pf0 = *reinterpret_cast<const bhalf8*>(&Ps[m0w + l15][ks * 32 + quad * 8]);
            bhalf8 pf1 = *reinterpret_cast<const bhalf8*>(&Ps[m0w + 16 + l15][ks * 32 + quad * 8]);
#pragma unroll
            for (int nt = 0; nt < 4; ++nt) {
                bhalf8 vf = *reinterpret_cast<const bhalf8*>(&Vs[n0v + nt * 16 + l15][ks * 32 + quad * 8]);
                oacc[0][nt] = __builtin_amdgcn_mfma_f32_16x16x32_bf16(pf0, vf, oacc[0][nt], 0, 0, 0);
                oacc[1][nt] = __builtin_amdgcn_mfma_f32_16x16x32_bf16(pf1, vf, oacc[1][nt], 0, 0, 0);
            }
        }
        __syncthreads();   // protect Ks/Vs re-staging
    }

    if ((tid & 3) == 0) lsum[srow_sm] = l_i;
    __syncthreads();
#pragma unroll
    for (int mt = 0; mt < 2; ++mt)
#pragma unroll
        for (int r = 0; r < 4; ++r) {
            int row = m0w + mt * 16 + quad * 4 + r;
            float inv = 1.0f / lsum[row];
#pragma unroll
            for (int nt = 0; nt < 4; ++nt)
                attn_out[qkbase + (long)row * 2048 + n0v + nt * 16 + l15] = oacc[mt][nt][r] * inv;
        }
}

// ---------------------------------------------------------------------------
// fq/fk/fv in one launch (blockIdx.y = mode): silu (+affine q/k) (+L2 norm q/k)
// ---------------------------------------------------------------------------
__global__ __launch_bounds__(128) void fqkv_kernel(
    const float* __restrict__ qkv, const float* __restrict__ qk_scale,
    const float* __restrict__ qk_offset, u16* __restrict__ fq,
    u16* __restrict__ fk, u16* __restrict__ fv)
{
    int mode = blockIdx.y;
    int bid = blockIdx.x;
    int nh = bid & 3;
    int row = bid >> 2;
    const float* x = &qkv[(long)row * 6144 + mode * 2048 + nh * 512];
    __shared__ float red[128];
    float vals[4];
    float ss = 0.f;
#pragma unroll
    for (int ii = 0; ii < 4; ++ii) {
        int i = threadIdx.x + ii * 128;
        float v = x[i];
        float sg = 1.f / (1.f + expf(-v));
        float sv = v * sg;
        if (mode < 2) {
            int dcol = nh * 512 + i;
            sv = sv * qk_scale[dcol * 2 + mode] + qk_offset[dcol * 2 + mode];
        }
        vals[ii] = sv;
        ss += sv * sv;
    }
    float invn = 1.0f;
    if (mode < 2) {
        red[threadIdx.x] = ss; __syncthreads();
        for (int s_ = 64; s_ > 0; s_ >>= 1) {
            if (threadIdx.x < s_) red[threadIdx.x] += red[threadIdx.x + s_];
            __syncthreads();
        }
        invn = 1.0f / (sqrtf(red[0]) + 1e-12f);
    }
    u16* base = (mode == 0) ? fq : (mode == 1) ? fk : fv;
    u16* o = &base[(long)row * 2048 + nh * 512];
#pragma unroll
    for (int ii = 0; ii < 4; ++ii) o[threadIdx.x + ii * 128] = f2bf(vals[ii] * invn);
}

// ---------------------------------------------------------------------------
// fast-weight init: tile (4,512,512) x b=2 -> (8,512,512) fp32
// ---------------------------------------------------------------------------
__global__ void winit(const float* __restrict__ w0, const float* __restrict__ w1,
                      const float* __restrict__ w2, float* __restrict__ w0b,
                      float* __restrict__ w1b, float* __restrict__ w2b)
{
    long idx = (long)blockIdx.x * 256 + threadIdx.x;
    long src = ((idx >> 18) & 3) * 262144 + (idx & 262143);
    w0b[idx] = w0[src];
    w1b[idx] = w1[src];
    w2b[idx] = w2[src];
}

// ---------------------------------------------------------------------------
// scan elementwise 1: reads gate|hpre from T12 (1024-wide), dh from T3;
// writes dgate*l0 / dhpre*l2 in place into T12, fv*l1 into T3, hid into T4.
// ---------------------------------------------------------------------------
__global__ void scan_ew1(float* T12, float* T3, const u16* fvb,
                         const float* lr, int c0, float* T4)
{
    long idx = (long)blockIdx.x * 256 + threadIdx.x;  // 8*1024*512
    int f = (int)(idx & 511);
    long r = idx >> 9;          // z*1024 + ci
    int ci = (int)(r & 1023);
    int z = (int)(r >> 10);
    int b_ = z >> 2, h = z & 3;
    long srow = (long)b_ * S + (long)c0 * CHUNK + ci;
    long base12 = r * 1024;
    float g = T12[base12 + f];
    float hp = T12[base12 + 512 + f];
    float dh = T3[idx];
    float sg = 1.f / (1.f + expf(-g));
    float silu_g = g * sg;
    float hid = silu_g * hp;
    float dgate = dh * hp * (sg * (1.f + g * (1.f - sg)));
    float dhpre = dh * silu_g;
    float l0 = lr[srow * 12 + h];
    float l1 = lr[srow * 12 + 4 + h];
    float l2 = lr[srow * 12 + 8 + h];
    float fvv = bf2f(fvb[srow * 2048 + h * 512 + f]);
    T12[base12 + f] = dgate * l0;
    T12[base12 + 512 + f] = dhpre * l2;
    T3[idx] = fvv * l1;
    T4[idx] = hid;
}

// scan elementwise 2 + cvt: hq = bf16(silu(gq) * hq2), gq|hq2 in T12
__global__ void scan_ew2c(const float* __restrict__ T12, u16* __restrict__ hq)
{
    long idx = (long)blockIdx.x * 256 + threadIdx.x;   // 8*1024*512
    int f = (int)(idx & 511);
    long r = idx >> 9;
    long base12 = r * 1024;
    float g = T12[base12 + f];
    float h2 = T12[base12 + 512 + f];
    float v = g * (1.f / (1.f + expf(-g))) * h2;
    hq[idx] = f2bf(v);
}

// ---------------------------------------------------------------------------
// ttt rmsnorm added into attn_out in place
// ---------------------------------------------------------------------------
__global__ __launch_bounds__(128) void ttt_norm_add(
    const float* __restrict__ ttt, const float* __restrict__ w, float* attnX)
{
    int bid = blockIdx.x;
    int h = bid & 3;
    int row = bid >> 2;
    const float* x = &ttt[(long)row * 2048 + h * 512];
    __shared__ float red[128];
    float v[4];
    float ss = 0.f;
#pragma unroll
    for (int ii = 0; ii < 4; ++ii) {
        v[ii] = x[threadIdx.x + ii * 128];
        ss += v[ii] * v[ii];
    }
    red[threadIdx.x] = ss; __syncthreads();
    for (int s_ = 64; s_ > 0; s_ >>= 1) {
        if (threadIdx.x < s_) red[threadIdx.x] += red[threadIdx.x + s_];
        __syncthreads();
    }
    float sc = rsqrtf(red[0] / 512.f + 1e-6f);
    float* o = &attnX[(long)row * 2048 + h * 512];
#pragma unroll
    for (int ii = 0; ii < 4; ++ii) {
        int i = threadIdx.x + ii * 128;
        o[i] = o[i] + v[ii] * sc * w[i];
    }
}

// ---------------------------------------------------------------------------
extern "C" void kernel_launch(void* const* d_in, const int* in_sizes, int n_in,
                              void* d_out, int out_size, void* d_ws, size_t ws_size,
                              hipStream_t stream)
{
    const float* hs        = (const float*)d_in[0];
    const float* Wqkv      = (const float*)d_in[1];
    const float* Wo        = (const float*)d_in[2];
    const float* q_norm_w  = (const float*)d_in[3];
    const float* k_norm_w  = (const float*)d_in[4];
    const float* w0        = (const float*)d_in[5];
    const float* w1        = (const float*)d_in[6];
    const float* w2        = (const float*)d_in[7];
    const float* lr_w      = (const float*)d_in[8];
    const float* lr_b      = (const float*)d_in[9];
    const float* qk_scale  = (const float*)d_in[10];
    const float* qk_offset = (const float*)d_in[11];
    const float* ttt_w     = (const float*)d_in[12];
    float* out = (float*)d_out;
    float* ws = (float*)d_ws;

    // ---- workspace (fp32 units), total 65,060,864 floats = 248.2 MiB -------
    const long F_QKV = 0;          // qkv fp32 (25,165,824); later:
    const long F_TTT = 0;          //   ttt fp32 (8,388,608)
    const long F_T1  = 8388608;    //   T12 fp32 (8,388,608 = old T1+T2)
    const long F_T3  = 16777216;   //   T3, T4 fp32 (2 x 4,194,304)
    const long F_T4  = 20971520;
    const long F_AQ  = 25165824;   // hs_b -> aq bf16 (4M fl) + vt bf16 (4M fl) -> fq_b | fk_b
    const long F_AK  = 33554432;   // Wqkv_b -> ak bf16 -> fv_b | hq_b | fkt
    const long F_ATT = 41943040;   // attX fp32 (8,388,608)
    const long F_TTa = 50331648;   // transposed bf16 temp A (2,097,152)
    const long F_TTb = 52428800;   // transposed bf16 temp B (2,097,152)
    const long F_W0  = 54525952;   // weights fp32 (3 x 2,097,152)
    const long F_W1  = 56623104;
    const long F_W2  = 58720256;
    const long F_W02B= 60817408;   // packed w0|w2 bf16 (8,1024,512) = 2,097,152 fl
    const long F_W1B = 62914560;   // w1 bf16 snapshot (1,048,576 fl)
    const long F_W1T = 63963136;   // w1^T bf16 (1,048,576 fl)
    const long F_LR  = 65011712;   // end 65,060,864

    u16* hs_b   = (u16*)(ws + F_AQ);
    u16* wqkv_b = (u16*)(ws + F_AK);
    u16* aq_b   = (u16*)(ws + F_AQ);             // bf16, 8,388,608 elems
    u16* ak_b   = (u16*)(ws + F_AK);
    u16* vt_b   = (u16*)(ws + F_AQ + 4194304);   // ends exactly at F_AK
    u16* fq_b   = (u16*)(ws + F_AQ);
    u16* fk_b   = (u16*)(ws + F_AQ + 4194304);
    u16* fv_b   = (u16*)(ws + F_AK);
    u16* hq_b   = (u16*)(ws + F_AK + 4194304);
    u16* fkt_b  = (u16*)(ws + F_AK + 6291456);
    u16* tta    = (u16*)(ws + F_TTa);
    u16* ttb    = (u16*)(ws + F_TTb);
    u16* w02b_u = (u16*)(ws + F_W02B);
    u16* w1b_u  = (u16*)(ws + F_W1B);
    u16* w1t_u  = (u16*)(ws + F_W1T);
    u16* x_b    = (u16*)(ws + F_T1);   // after scan
    u16* wo_b   = (u16*)(ws + F_T3);   // after scan

    // 1. qkv = hs @ Wqkv^T  (bf16 MFMA)
    cvt_bf16<<<8192, 256, 0, stream>>>(hs, hs_b, 8388608);
    cvt_bf16<<<12288, 256, 0, stream>>>(Wqkv, wqkv_b, 12582912);
    gemm_mfma<<<dim3(48, 32, 1), 256, 0, stream>>>(
        hs_b, 2048, 0, 0, wqkv_b, 2048, 0, 0, ws + F_QKV, 6144, 0, 0, 2048, 0);
    // 2. lr
    lr_kernel<<<4096, 256, 0, stream>>>(hs, lr_w, lr_b, ws + F_LR);
    // 3. rmsnorm + rope -> bf16
    rmsnorm_rope<<<4096, 256, 0, stream>>>(ws + F_QKV, 0,    q_norm_w, aq_b);
    rmsnorm_rope<<<4096, 256, 0, stream>>>(ws + F_QKV, 2048, k_norm_w, ak_b);
    // 3b. V transpose for attention
    vt_prep<<<dim3(32, 2, 32), 256, 0, stream>>>(ws + F_QKV, vt_b);
    // 4. attention (bf16 MFMA)
    attn_mfma<<<dim3(32, 16, 2), 256, 0, stream>>>(aq_b, ak_b, vt_b, ws + F_ATT);
    // 5. fq/fk/fv bf16 (one launch, 3 modes)
    fqkv_kernel<<<dim3(16384, 3), 128, 0, stream>>>(
        ws + F_QKV, qk_scale, qk_offset, fq_b, fk_b, fv_b);
    // 6. fast-weight init (fp32 masters)
    winit<<<8192, 256, 0, stream>>>(w0, w1, w2, ws + F_W0, ws + F_W1, ws + F_W2);

    for (int c0 = 0; c0 < 2; ++c0) {
        const long cOff = (long)c0 * 2097152;           // chunk offset in bf16 elems
        // packed bf16 snapshots: w02 = [w0; w2] rows, plus w1^T
        cvt_pack<<<2048, 256, 0, stream>>>(ws + F_W0, w02b_u, 0);
        cvt_pack<<<2048, 256, 0, stream>>>(ws + F_W2, w02b_u, 1);
        transpose_cvt<float><<<dim3(8, 8, 8), 256, 0, stream>>>(
            ws + F_W1, 512, 1048576, 262144, w1t_u, 512, 1048576, 262144);
        // fk^T for the updates
        transpose_cvt<u16><<<dim3(8, 16, 8), 256, 0, stream>>>(
            fk_b + cOff, 2048, 4194304, 512, fkt_b, 1024, 2097152, 524288);
        // gate|hpre fused (N=1024) + dh
        gemm_mfma<<<dim3(8, 8, 8), 256, 0, stream>>>(
            fk_b + cOff, 2048, 4194304, 512, w02b_u, 512, 2097152, 524288,
            ws + F_T1, 1024, 4194304, 1048576, 512, 0);
        gemm_mfma<<<dim3(4, 8, 8), 256, 0, stream>>>(
            fv_b + cOff, 2048, 4194304, 512, w1t_u, 512, 1048576, 262144,
            ws + F_T3, 512, 2097152, 524288, 512, 0);
        // elementwise (in-place into T12/T3, plus T4)
        scan_ew1<<<16384, 256, 0, stream>>>(ws + F_T1, ws + F_T3, fv_b,
                                            ws + F_LR, c0, ws + F_T4);
        // transpose pairs -> tta/ttb; weight updates (64-tile GEMMs, grid 512)
        transpose_cvt2<<<dim3(8, 16, 16), 256, 0, stream>>>(
            ws + F_T1, ws + F_T1 + 512, 1024, 1048576, tta, ttb, 1024, 524288);
        gemm_mfma64<<<dim3(8, 8, 8), 256, 0, stream>>>(
            tta, 1024, 2097152, 524288, fkt_b, 1024, 2097152, 524288,
            ws + F_W0, 512, 1048576, 262144, 1024, 1);
        gemm_mfma64<<<dim3(8, 8, 8), 256, 0, stream>>>(
            ttb, 1024, 2097152, 524288, fkt_b, 1024, 2097152, 524288,
            ws + F_W2, 512, 1048576, 262144, 1024, 1);
        transpose_cvt2<<<dim3(8, 16, 16), 256, 0, stream>>>(
            ws + F_T3, ws + F_T4, 512, 524288, tta, ttb, 1024, 524288);
        gemm_mfma64<<<dim3(8, 8, 8), 256, 0, stream>>>(
            tta, 1024, 2097152, 524288, ttb, 1024, 2097152, 524288,
            ws + F_W1, 512, 1048576, 262144, 1024, 1);
        // query pass with updated weights (gq|hq2 fused)
        cvt_pack<<<2048, 256, 0, stream>>>(ws + F_W0, w02b_u, 0);
        cvt_pack<<<2048, 256, 0, stream>>>(ws + F_W2, w02b_u, 1);
        cvt_bf16<<<2048, 256, 0, stream>>>(ws + F_W1, w1b_u, 2097152);
        gemm_mfma<<<dim3(8, 8, 8), 256, 0, stream>>>(
            fq_b + cOff, 2048, 4194304, 512, w02b_u, 512, 2097152, 524288,
            ws + F_T1, 1024, 4194304, 1048576, 512, 0);
        scan_ew2c<<<16384, 256, 0, stream>>>(ws + F_T1, hq_b);
        // oi = hq @ w1^T -> ttt (strided (b,s,NH,fd))
        gemm_mfma<<<dim3(4, 8, 8), 256, 0, stream>>>(
            hq_b, 512, 2097152, 524288, w1b_u, 512, 1048576, 262144,
            ws + F_TTT + cOff, 2048, 4194304, 512, 512, 0);
    }

    // 8. ttt rmsnorm + add into attX
    ttt_norm_add<<<16384, 128, 0, stream>>>(ws + F_TTT, ttt_w, ws + F_ATT);
    // 9. out = X @ Wo^T  (bf16 MFMA; X_b/Wo_b reuse dead T region)
    cvt_bf16<<<8192, 256, 0, stream>>>(ws + F_ATT, x_b, 8388608);
    cvt_bf16<<<4096, 256, 0, stream>>>(Wo, wo_b, 4194304);
    gemm_mfma<<<dim3(16, 32, 1), 256, 0, stream>>>(
        x_b, 2048, 0, 0, wo_b, 2048, 0, 0, out, 2048, 0, 0, 2048, 0);
}

// Round 7
// 912.174 us; speedup vs baseline: 2.1920x; 1.1038x over previous
//
#include <hip/hip_runtime.h>
#include <hip/hip_bf16.h>
#include <math.h>

#define S 2048
#define NH 4
#define FD 512
#define CHUNK 1024
#define BASE_LR_INV -6.9072552373f

typedef unsigned short u16;
typedef unsigned int u32;
typedef short bhalf8 __attribute__((ext_vector_type(8)));   // 8 bf16 = 4 VGPRs
typedef float floatx4 __attribute__((ext_vector_type(4)));

__device__ __forceinline__ u16 f2bf(float f) {               // RNE fp32->bf16
    u32 x = __float_as_uint(f);
    return (u16)((x + 0x7FFFu + ((x >> 16) & 1u)) >> 16);
}
__device__ __forceinline__ float bf2f(u16 u) {
    return __uint_as_float(((u32)u) << 16);
}
__device__ __forceinline__ float ldval(const float* p) { return *p; }
__device__ __forceinline__ float ldval(const u16* p) { return bf2f(*p); }

// async global->LDS, 16B per lane. LDS dest must be wave-uniform base
// (HW writes base + lane*16); global src is per-lane.
__device__ __forceinline__ void gl_lds16(const u16* g, u16* l)
{
    __builtin_amdgcn_global_load_lds(
        (const __attribute__((address_space(1))) void*)g,
        (__attribute__((address_space(3))) void*)l, 16, 0, 0);
}

// bijective XCD-contiguous block swizzle (T1). Requires nwg % 8 == 0 (guarded).
__device__ __forceinline__ void xcd_swizzle(int& bx, int& by, int& bz)
{
    long gx = gridDim.x, gy = gridDim.y;
    long nwg = gx * gy * gridDim.z;
    long flat = blockIdx.x + gx * (blockIdx.y + gy * blockIdx.z);
    if ((nwg & 7) == 0) {
        long cpx = nwg >> 3;
        flat = (flat & 7) * cpx + (flat >> 3);
    }
    bx = (int)(flat % gx);
    long t = flat / gx;
    by = (int)(t % gy);
    bz = (int)(t / gy);
}

// ---------------------------------------------------------------------------
// bf16 MFMA GEMM:  C(fp32) = A @ B^T, A:(M,K) bf16 lda, B:(N,K) bf16 ldb.
// 128x128 block tile, 256 thr = 4 waves (2x2 of 64x64), BK=32, double-buffered
// LDS with global_load_lds prefetch. acc_flag: C += result.
// Batched: ptr += (z>>2)*offO + (z&3)*offI.  M,N mult of 128; K mult of 64.
// ---------------------------------------------------------------------------
__global__ __launch_bounds__(256) void gemm_mfma(
    const u16* __restrict__ A, int lda, long offAo, long offAi,
    const u16* __restrict__ B, int ldb, long offBo, long offBi,
    float* __restrict__ C, int ldc, long offCo, long offCi, int K, int acc_flag)
{
    int bx, by, bz;
    xcd_swizzle(bx, by, bz);
    int z = bz;
    A += (long)(z >> 2) * offAo + (long)(z & 3) * offAi;
    B += (long)(z >> 2) * offBo + (long)(z & 3) * offBi;
    C += (long)(z >> 2) * offCo + (long)(z & 3) * offCi;
    __shared__ u16 As0[128][32], Bs0[128][32];   // linear: required by global_load_lds
    __shared__ u16 As1[128][32], Bs1[128][32];
    const int tid = threadIdx.x;
    const int wid = tid >> 6, lane = tid & 63;
    const int quad = lane >> 4, l15 = lane & 15;
    const int m0w = (wid >> 1) * 64, n0w = (wid & 1) * 64;
    const int row0 = by * 128, col0 = bx * 128;
    // staging lane map: chunk = 16 rows x 32 cols (1 KiB); lane l -> row l>>2, col (l&3)*8
    const int srow = lane >> 2, scol = (lane & 3) * 8;
    const int ca = wid * 16, cb = (wid + 4) * 16;   // this wave's two chunk rows

    const u16* gA0 = &A[(long)(row0 + ca + srow) * lda + scol];
    const u16* gA1 = &A[(long)(row0 + cb + srow) * lda + scol];
    const u16* gB0 = &B[(long)(col0 + ca + srow) * ldb + scol];
    const u16* gB1 = &B[(long)(col0 + cb + srow) * ldb + scol];

    floatx4 acc[4][4];
#pragma unroll
    for (int a = 0; a < 4; ++a)
#pragma unroll
        for (int b = 0; b < 4; ++b) acc[a][b] = {0.f, 0.f, 0.f, 0.f};

#define GSTAGE(AS, BS, kk) do { \
    gl_lds16(gA0 + (kk), &AS[ca][0]); \
    gl_lds16(gA1 + (kk), &AS[cb][0]); \
    gl_lds16(gB0 + (kk), &BS[ca][0]); \
    gl_lds16(gB1 + (kk), &BS[cb][0]); } while (0)

#define GCOMP(AS, BS) do { \
    bhalf8 af[4], bf[4]; \
    _Pragma("unroll") \
    for (int mt = 0; mt < 4; ++mt) \
        af[mt] = *reinterpret_cast<const bhalf8*>(&AS[m0w + mt * 16 + l15][quad * 8]); \
    _Pragma("unroll") \
    for (int nt = 0; nt < 4; ++nt) \
        bf[nt] = *reinterpret_cast<const bhalf8*>(&BS[n0w + nt * 16 + l15][quad * 8]); \
    _Pragma("unroll") \
    for (int mt = 0; mt < 4; ++mt) \
        _Pragma("unroll") \
        for (int nt = 0; nt < 4; ++nt) \
            acc[mt][nt] = __builtin_amdgcn_mfma_f32_16x16x32_bf16( \
                af[mt], bf[nt], acc[mt][nt], 0, 0, 0); } while (0)

    const int nt = K >> 5;          // even: K % 64 == 0
    GSTAGE(As0, Bs0, 0);
    for (int t = 0; t < nt; t += 2) {
        __syncthreads();
        GSTAGE(As1, Bs1, (t + 1) * 32);   // prefetch flies under compute
        GCOMP(As0, Bs0);
        __syncthreads();
        if (t + 2 < nt) GSTAGE(As0, Bs0, (t + 2) * 32);
        GCOMP(As1, Bs1);
    }
#undef GSTAGE
#undef GCOMP

#pragma unroll
    for (int mt = 0; mt < 4; ++mt)
#pragma unroll
        for (int nt = 0; nt < 4; ++nt) {
            int col = col0 + n0w + nt * 16 + l15;
#pragma unroll
            for (int r = 0; r < 4; ++r) {
                int row = row0 + m0w + mt * 16 + quad * 4 + r;
                long off = (long)row * ldc + col;
                float v = acc[mt][nt][r];
                C[off] = acc_flag ? (C[off] + v) : v;
            }
        }
}

// ---------------------------------------------------------------------------
// 64x64-tile variant for small GEMMs (M,N mult of 64; K mult of 64).
// ---------------------------------------------------------------------------
__global__ __launch_bounds__(256) void gemm_mfma64(
    const u16* __restrict__ A, int lda, long offAo, long offAi,
    const u16* __restrict__ B, int ldb, long offBo, long offBi,
    float* __restrict__ C, int ldc, long offCo, long offCi, int K, int acc_flag)
{
    int bx, by, bz;
    xcd_swizzle(bx, by, bz);
    int z = bz;
    A += (long)(z >> 2) * offAo + (long)(z & 3) * offAi;
    B += (long)(z >> 2) * offBo + (long)(z & 3) * offBi;
    C += (long)(z >> 2) * offCo + (long)(z & 3) * offCi;
    __shared__ u16 As0[64][32], Bs0[64][32];
    __shared__ u16 As1[64][32], Bs1[64][32];
    const int tid = threadIdx.x;
    const int wid = tid >> 6, lane = tid & 63;
    const int quad = lane >> 4, l15 = lane & 15;
    const int m0w = (wid >> 1) * 32, n0w = (wid & 1) * 32;
    const int row0 = by * 64, col0 = bx * 64;
    const int srow = lane >> 2, scol = (lane & 3) * 8;
    const int ca = wid * 16;          // wave's chunk row (4 x 16 = 64)

    const u16* gA0 = &A[(long)(row0 + ca + srow) * lda + scol];
    const u16* gB0 = &B[(long)(col0 + ca + srow) * ldb + scol];

    floatx4 acc[2][2];
#pragma unroll
    for (int a = 0; a < 2; ++a)
#pragma unroll
        for (int b = 0; b < 2; ++b) acc[a][b] = {0.f, 0.f, 0.f, 0.f};

#define GSTAGE64(AS, BS, kk) do { \
    gl_lds16(gA0 + (kk), &AS[ca][0]); \
    gl_lds16(gB0 + (kk), &BS[ca][0]); } while (0)

#define GCOMP64(AS, BS) do { \
    bhalf8 af[2], bf[2]; \
    _Pragma("unroll") \
    for (int mt = 0; mt < 2; ++mt) \
        af[mt] = *reinterpret_cast<const bhalf8*>(&AS[m0w + mt * 16 + l15][quad * 8]); \
    _Pragma("unroll") \
    for (int nt = 0; nt < 2; ++nt) \
        bf[nt] = *reinterpret_cast<const bhalf8*>(&BS[n0w + nt * 16 + l15][quad * 8]); \
    _Pragma("unroll") \
    for (int mt = 0; mt < 2; ++mt) \
        _Pragma("unroll") \
        for (int nt = 0; nt < 2; ++nt) \
            acc[mt][nt] = __builtin_amdgcn_mfma_f32_16x16x32_bf16( \
                af[mt], bf[nt], acc[mt][nt], 0, 0, 0); } while (0)

    const int nt = K >> 5;          // even
    GSTAGE64(As0, Bs0, 0);
    for (int t = 0; t < nt; t += 2) {
        __syncthreads();
        GSTAGE64(As1, Bs1, (t + 1) * 32);
        GCOMP64(As0, Bs0);
        __syncthreads();
        if (t + 2 < nt) GSTAGE64(As0, Bs0, (t + 2) * 32);
        GCOMP64(As1, Bs1);
    }
#undef GSTAGE64
#undef GCOMP64

#pragma unroll
    for (int mt = 0; mt < 2; ++mt)
#pragma unroll
        for (int nt = 0; nt < 2; ++nt) {
            int col = col0 + n0w + nt * 16 + l15;
#pragma unroll
            for (int r = 0; r < 4; ++r) {
                int row = row0 + m0w + mt * 16 + quad * 4 + r;
                long off = (long)row * ldc + col;
                float v = acc[mt][nt][r];
                C[off] = acc_flag ? (C[off] + v) : v;
            }
        }
}

// ---------------------------------------------------------------------------
// flat fp32 -> bf16 convert (n mult of 4)
// ---------------------------------------------------------------------------
__global__ __launch_bounds__(256) void cvt_bf16(
    const float* __restrict__ in, u16* __restrict__ out, long n)
{
    long i = ((long)blockIdx.x * 256 + threadIdx.x) * 4;
    if (i >= n) return;
    float4 v = *reinterpret_cast<const float4*>(&in[i]);
    ushort4 o;
    o.x = f2bf(v.x); o.y = f2bf(v.y); o.z = f2bf(v.z); o.w = f2bf(v.w);
    *reinterpret_cast<ushort4*>(&out[i]) = o;
}

// ---------------------------------------------------------------------------
// pack master (8,512,512) fp32 -> (8,1024,512) bf16 rows [half*512, half*512+512)
// ---------------------------------------------------------------------------
__global__ __launch_bounds__(256) void cvt_pack(
    const float* __restrict__ in, u16* __restrict__ out, int half)
{
    long idx = ((long)blockIdx.x * 256 + threadIdx.x) * 4;   // over 2,097,152
    int col = (int)(idx & 511);
    long r = idx >> 9;
    int row = (int)(r & 511);
    int z = (int)(r >> 9);
    float4 v = *reinterpret_cast<const float4*>(&in[idx]);
    ushort4 o;
    o.x = f2bf(v.x); o.y = f2bf(v.y); o.z = f2bf(v.z); o.w = f2bf(v.w);
    long dst = ((long)z * 1024 + half * 512 + row) * 512 + col;
    *reinterpret_cast<ushort4*>(&out[dst]) = o;
}

// ---------------------------------------------------------------------------
// batched transpose + cvt: in[z] (R,C) ld=ldin  ->  out[z] (C,R) bf16 ld=ldout
// ---------------------------------------------------------------------------
template <typename TIN>
__global__ __launch_bounds__(256) void transpose_cvt(
    const TIN* __restrict__ in, int ldin, long inOo, long inOi,
    u16* __restrict__ out, int ldout, long outOo, long outOi)
{
    int z = blockIdx.z;
    in  += (long)(z >> 2) * inOo + (long)(z & 3) * inOi;
    out += (long)(z >> 2) * outOo + (long)(z & 3) * outOi;
    int r0 = blockIdx.y * 64, c0 = blockIdx.x * 64;
    __shared__ float t[64][65];
    for (int i = threadIdx.x; i < 4096; i += 256) {
        int r = i >> 6, c = i & 63;
        t[r][c] = ldval(&in[(long)(r0 + r) * ldin + c0 + c]);
    }
    __syncthreads();
    for (int i = threadIdx.x; i < 4096; i += 256) {
        int r = i >> 6, c = i & 63;
        out[(long)(c0 + r) * ldout + r0 + c] = f2bf(t[c][r]);
    }
}

// ---------------------------------------------------------------------------
// V transpose for attention: qkv V slice (b,s,h,128) fp32 -> vt (b,h,128,s) bf16
// ---------------------------------------------------------------------------
__global__ __launch_bounds__(256) void vt_prep(
    const float* __restrict__ qkv, u16* __restrict__ vt)
{
    int z = blockIdx.z;          // b*16 + h
    int b_ = z >> 4, h = z & 15;
    int s0 = blockIdx.x * 64, d0 = blockIdx.y * 64;
    __shared__ float t[64][65];
    const float* src = &qkv[(long)(b_ * S) * 6144 + 4096 + h * 128 + d0];
    for (int i = threadIdx.x; i < 4096; i += 256) {
        int r = i >> 6, c = i & 63;      // r: s, c: d
        t[r][c] = src[(long)(s0 + r) * 6144 + c];
    }
    __syncthreads();
    u16* dst = &vt[((long)z * 128 + d0) * 2048 + s0];
    for (int i = threadIdx.x; i < 4096; i += 256) {
        int r = i >> 6, c = i & 63;      // r: d, c: s
        dst[(long)r * 2048 + c] = f2bf(t[c][r]);
    }
}

// ---------------------------------------------------------------------------
// lr = softplus(hs @ lr_w^T + lr_b + BASE_LR_INV)  -> (4096, 12)
// ---------------------------------------------------------------------------
__global__ __launch_bounds__(256) void lr_kernel(
    const float* __restrict__ hs, const float* __restrict__ lr_w,
    const float* __restrict__ lr_b, float* __restrict__ lr)
{
    int row = blockIdx.x;
    __shared__ float hrow[2048];
    for (int i = threadIdx.x; i < 2048; i += 256) hrow[i] = hs[(long)row * 2048 + i];
    __syncthreads();
    int wid = threadIdx.x >> 6, lane = threadIdx.x & 63;
    for (int j = wid; j < 12; j += 4) {
        const float* wrow = &lr_w[(long)j * 2048];
        float ss = 0.f;
        for (int i = lane; i < 2048; i += 64) ss += hrow[i] * wrow[i];
#pragma unroll
        for (int off = 32; off > 0; off >>= 1) ss += __shfl_down(ss, off);
        if (lane == 0) {
            float x = ss + lr_b[j] + BASE_LR_INV;
            lr[(long)row * 12 + j] = (x > 20.f) ? x : log1pf(expf(x));
        }
    }
}

// ---------------------------------------------------------------------------
// rmsnorm over d=2048 + RoPE per head (hd=128) -> packed bf16 (b,s,16,128)
// ---------------------------------------------------------------------------
__global__ __launch_bounds__(256) void rmsnorm_rope(
    const float* __restrict__ qkv, int colOff, const float* __restrict__ w,
    u16* __restrict__ out)
{
    int row = blockIdx.x;            // b*s
    int si = row & (S - 1);
    const float* x = &qkv[(long)row * 6144 + colOff];
    __shared__ float xn[2048];
    __shared__ float red[256];
    __shared__ float cst[64], snt[64];
    if (threadIdx.x < 64) {
        float inv_freq = powf(500000.0f, -(float)threadIdx.x / 64.0f);
        float ang = (float)si * inv_freq;
        float sn, cs;
        sincosf(ang, &sn, &cs);
        cst[threadIdx.x] = cs;
        snt[threadIdx.x] = sn;
    }
    float ss = 0.f;
    for (int i = threadIdx.x; i < 2048; i += 256) { float v = x[i]; ss += v * v; }
    red[threadIdx.x] = ss; __syncthreads();
    for (int s_ = 128; s_ > 0; s_ >>= 1) {
        if (threadIdx.x < s_) red[threadIdx.x] += red[threadIdx.x + s_];
        __syncthreads();
    }
    float scale = rsqrtf(red[0] / 2048.f + 1e-6f);
    for (int i = threadIdx.x; i < 2048; i += 256) xn[i] = x[i] * scale * w[i];
    __syncthreads();
    for (int i = threadIdx.x; i < 2048; i += 256) {
        int tt = i & 127;
        int t2 = tt & 63;
        float cs = cst[t2], sn = snt[t2];
        float v;
        if (tt < 64) v = xn[i] * cs - xn[i + 64] * sn;
        else         v = xn[i] * cs + xn[i - 64] * sn;
        out[(long)row * 2048 + i] = f2bf(v);
    }
}

// ---------------------------------------------------------------------------
// Flash-style sliding-window causal attention, bf16 MFMA.
// ---------------------------------------------------------------------------
__global__ __launch_bounds__(256) void attn_mfma(
    const u16* __restrict__ aq, const u16* __restrict__ ak,
    const u16* __restrict__ vt, float* __restrict__ attn_out)
{
    const int qt = blockIdx.x;   // 0..31
    const int h  = blockIdx.y;   // 0..15
    const int b_ = blockIdx.z;   // 0..1
    const int q0 = qt * 64;
    const int tid = threadIdx.x;
    const int wid = tid >> 6, lane = tid & 63;
    const int quad = lane >> 4, l15 = lane & 15;
    const int m0w = (wid >> 1) * 32;      // q rows for this wave
    const int n0w = (wid & 1) * 32;       // kv cols (QK phase)
    const int n0v = (wid & 1) * 64;       // d cols (PV phase)
    const float scale = 0.088388347648318447f;

    __shared__ u16  Ks[64][136];
    __shared__ float Ss[64][67];
    __shared__ u16  Ps[64][72];
    __shared__ u16  Vs[128][72];
    __shared__ float alphas[64];
    __shared__ float lsum[64];

    const long qkbase = (long)(b_ * S + q0) * 2048 + h * 128;
    const long vtbase = ((long)(b_ * 16 + h)) * 128 * 2048;

    // ---- stage Q tile into Ks, hoist Q fragments into registers ----
    {
        int r = tid >> 2, c = (tid & 3) * 32;
        const u16* g = &aq[qkbase + (long)r * 2048 + c];
#pragma unroll
        for (int o = 0; o < 32; o += 8)
            *reinterpret_cast<uint4*>(&Ks[r][c + o]) = *reinterpret_cast<const uint4*>(g + o);
    }
    __syncthreads();
    bhalf8 qf[2][4];
#pragma unroll
    for (int mt = 0; mt < 2; ++mt)
#pragma unroll
        for (int ks = 0; ks < 4; ++ks)
            qf[mt][ks] = *reinterpret_cast<const bhalf8*>(&Ks[m0w + mt * 16 + l15][ks * 32 + quad * 8]);
    __syncthreads();

    floatx4 oacc[2][4];
#pragma unroll
    for (int mt = 0; mt < 2; ++mt)
#pragma unroll
        for (int nt = 0; nt < 4; ++nt) oacc[mt][nt] = {0.f, 0.f, 0.f, 0.f};
    float m_i = -3.4e38f, l_i = 0.f;
    const int srow_sm = tid >> 2, scol_sm = (tid & 3) * 16;

    const int st = (qt >= 16) ? (qt - 16) : 0;
    for (int kt = st; kt <= qt; ++kt) {
        const int j0 = kt * 64;
        {
            int r = tid >> 2, c = (tid & 3) * 32;
            const u16* g = &ak[(long)(b_ * S + j0) * 2048 + h * 128 + (long)r * 2048 + c];
#pragma unroll
            for (int o = 0; o < 32; o += 8)
                *reinterpret_cast<uint4*>(&Ks[r][c + o]) = *reinterpret_cast<const uint4*>(g + o);
        }
        {
            int r = tid >> 1, c = (tid & 1) * 32;
            const u16* g = &vt[vtbase + (long)r * 2048 + j0 + c];
#pragma unroll
            for (int o = 0; o < 32; o += 8)
                *reinterpret_cast<uint4*>(&Vs[r][c + o]) = *reinterpret_cast<const uint4*>(g + o);
        }
        __syncthreads();

        floatx4 sacc[2][2];
#pragma unroll
        for (int mt = 0; mt < 2; ++mt)
#pragma unroll
            for (int nt = 0; nt < 2; ++nt) sacc[mt][nt] = {0.f, 0.f, 0.f, 0.f};
#pragma unroll
        for (int ks = 0; ks < 4; ++ks) {
            bhalf8 kf0 = *reinterpret_cast<const bhalf8*>(&Ks[n0w + l15][ks * 32 + quad * 8]);
            bhalf8 kf1 = *reinterpret_cast<const bhalf8*>(&Ks[n0w + 16 + l15][ks * 32 + quad * 8]);
            sacc[0][0] = __builtin_amdgcn_mfma_f32_16x16x32_bf16(qf[0][ks], kf0, sacc[0][0], 0, 0, 0);
            sacc[0][1] = __builtin_amdgcn_mfma_f32_16x16x32_bf16(qf[0][ks], kf1, sacc[0][1], 0, 0, 0);
            sacc[1][0] = __builtin_amdgcn_mfma_f32_16x16x32_bf16(qf[1][ks], kf0, sacc[1][0], 0, 0, 0);
            sacc[1][1] = __builtin_amdgcn_mfma_f32_16x16x32_bf16(qf[1][ks], kf1, sacc[1][1], 0, 0, 0);
        }
#pragma unroll
        for (int mt = 0; mt < 2; ++mt)
#pragma unroll
            for (int nt = 0; nt < 2; ++nt)
#pragma unroll
                for (int r = 0; r < 4; ++r) {
                    int row = m0w + mt * 16 + quad * 4 + r;
                    int col = n0w + nt * 16 + l15;
                    int i_abs = q0 + row, j_abs = j0 + col;
                    bool valid = (j_abs <= i_abs) && (i_abs - j_abs < 1024);
                    Ss[row][col] = valid ? sacc[mt][nt][r] * scale : -3.4e38f;
                }
        __syncthreads();

        {
            float sv[16];
            float mx = -3.4e38f;
#pragma unroll
            for (int j = 0; j < 16; ++j) {
                sv[j] = Ss[srow_sm][scol_sm + j];
                mx = fmaxf(mx, sv[j]);
            }
            mx = fmaxf(mx, __shfl_xor(mx, 1));
            mx = fmaxf(mx, __shfl_xor(mx, 2));
            float m_new = fmaxf(m_i, mx);
            float alpha = expf(m_i - m_new);
            float psum = 0.f;
#pragma unroll
            for (int j = 0; j < 16; ++j) {
                float p = (sv[j] > -1e30f) ? expf(sv[j] - m_new) : 0.f;
                Ps[srow_sm][scol_sm + j] = f2bf(p);
                psum += p;
            }
            psum += __shfl_xor(psum, 1);
            psum += __shfl_xor(psum, 2);
            l_i = l_i * alpha + psum;
            m_i = m_new;
            if ((tid & 3) == 0) alphas[srow_sm] = alpha;
        }
        __syncthreads();

#pragma unroll
        for (int mt = 0; mt < 2; ++mt)
#pragma unroll
            for (int r = 0; r < 4; ++r) {
                float al = alphas[m0w + mt * 16 + quad * 4 + r];
#pragma unroll
                for (int nt = 0; nt < 4; ++nt) oacc[mt][nt][r] *= al;
            }
#pragma unroll
        for (int ks = 0; ks < 2; ++ks) {
            bhalf8 pf0 = *reinterpret_cast<const bhalf8*>(&Ps[m0w + l15][ks * 32 + quad * 8]);
            bhalf8 pf1 = *reinterpret_cast<const bhalf8*>(&Ps[m0w + 16 + l15][ks * 32 + quad * 8]);
#pragma unroll
            for (int nt = 0; nt < 4; ++nt) {
                bhalf8 vf = *reinterpret_cast<const bhalf8*>(&Vs[n0v + nt * 16 + l15][ks * 32 + quad * 8]);
                oacc[0][nt] = __builtin_amdgcn_mfma_f32_16x16x32_bf16(pf0, vf, oacc[0][nt], 0, 0, 0);
                oacc[1][nt] = __builtin_amdgcn_mfma_f32_16x16x32_bf16(pf1, vf, oacc[1][nt], 0, 0, 0);
            }
        }
        __syncthreads();
    }

    if ((tid & 3) == 0) lsum[srow_sm] = l_i;
    __syncthreads();
#pragma unroll
    for (int mt = 0; mt < 2; ++mt)
#pragma unroll
        for (int r = 0; r < 4; ++r) {
            int row = m0w + mt * 16 + quad * 4 + r;
            float inv = 1.0f / lsum[row];
#pragma unroll
            for (int nt = 0; nt < 4; ++nt)
                attn_out[qkbase + (long)row * 2048 + n0v + nt * 16 + l15] = oacc[mt][nt][r] * inv;
        }
}

// ---------------------------------------------------------------------------
// fq/fk/fv in one launch (blockIdx.y = mode)
// ---------------------------------------------------------------------------
__global__ __launch_bounds__(128) void fqkv_kernel(
    const float* __restrict__ qkv, const float* __restrict__ qk_scale,
    const float* __restrict__ qk_offset, u16* __restrict__ fq,
    u16* __restrict__ fk, u16* __restrict__ fv)
{
    int mode = blockIdx.y;
    int bid = blockIdx.x;
    int nh = bid & 3;
    int row = bid >> 2;
    const float* x = &qkv[(long)row * 6144 + mode * 2048 + nh * 512];
    __shared__ float red[128];
    float vals[4];
    float ss = 0.f;
#pragma unroll
    for (int ii = 0; ii < 4; ++ii) {
        int i = threadIdx.x + ii * 128;
        float v = x[i];
        float sg = 1.f / (1.f + expf(-v));
        float sv = v * sg;
        if (mode < 2) {
            int dcol = nh * 512 + i;
            sv = sv * qk_scale[dcol * 2 + mode] + qk_offset[dcol * 2 + mode];
        }
        vals[ii] = sv;
        ss += sv * sv;
    }
    float invn = 1.0f;
    if (mode < 2) {
        red[threadIdx.x] = ss; __syncthreads();
        for (int s_ = 64; s_ > 0; s_ >>= 1) {
            if (threadIdx.x < s_) red[threadIdx.x] += red[threadIdx.x + s_];
            __syncthreads();
        }
        invn = 1.0f / (sqrtf(red[0]) + 1e-12f);
    }
    u16* base = (mode == 0) ? fq : (mode == 1) ? fk : fv;
    u16* o = &base[(long)row * 2048 + nh * 512];
#pragma unroll
    for (int ii = 0; ii < 4; ++ii) o[threadIdx.x + ii * 128] = f2bf(vals[ii] * invn);
}

// ---------------------------------------------------------------------------
// fast-weight init: tile (4,512,512) x b=2 -> (8,512,512) fp32
// ---------------------------------------------------------------------------
__global__ void winit(const float* __restrict__ w0, const float* __restrict__ w1,
                      const float* __restrict__ w2, float* __restrict__ w0b,
                      float* __restrict__ w1b, float* __restrict__ w2b)
{
    long idx = (long)blockIdx.x * 256 + threadIdx.x;
    long src = ((idx >> 18) & 3) * 262144 + (idx & 262143);
    w0b[idx] = w0[src];
    w1b[idx] = w1[src];
    w2b[idx] = w2[src];
}

// ---------------------------------------------------------------------------
// scan elementwise + fused transpose: reads gate|hpre (T12, ld 1024), dh (T3),
// fv, lr; writes FOUR transposed bf16 operands (z, 512 f, 1024 ci) ld 1024:
//   ta=(dgate*l0)^T  tb=(dhpre*l2)^T  tc=(fv*l1)^T  td=(hid)^T
// grid (8 f-tiles, 16 ci-tiles, 8 z), 256 thr. LDS tiles [64][66]: 2-way free.
// ---------------------------------------------------------------------------
__global__ __launch_bounds__(256) void scan_ew1t(
    const float* __restrict__ T12, const float* __restrict__ T3,
    const u16* __restrict__ fvb, const float* __restrict__ lr, int c0,
    u16* __restrict__ ta, u16* __restrict__ tb,
    u16* __restrict__ tc, u16* __restrict__ td)
{
    int f0 = blockIdx.x * 64, ci0 = blockIdx.y * 64, z = blockIdx.z;
    int b_ = z >> 2, h = z & 3;
    __shared__ u16 la[64][66], lb[64][66], lc[64][66], ldt[64][66];
    const int tr = threadIdx.x >> 4, tc4 = (threadIdx.x & 15) * 4;
#pragma unroll
    for (int it = 0; it < 4; ++it) {
        int r = tr + it * 16;            // local ci
        long row = (long)z * 1024 + ci0 + r;
        long srow = (long)b_ * S + (long)c0 * CHUNK + ci0 + r;
        float4 g4  = *reinterpret_cast<const float4*>(&T12[row * 1024 + f0 + tc4]);
        float4 hp4 = *reinterpret_cast<const float4*>(&T12[row * 1024 + 512 + f0 + tc4]);
        float4 dh4 = *reinterpret_cast<const float4*>(&T3[row * 512 + f0 + tc4]);
        ushort4 fv4 = *reinterpret_cast<const ushort4*>(&fvb[srow * 2048 + h * 512 + f0 + tc4]);
        float l0 = lr[srow * 12 + h];
        float l1 = lr[srow * 12 + 4 + h];
        float l2 = lr[srow * 12 + 8 + h];
        float gs[4]  = {g4.x, g4.y, g4.z, g4.w};
        float hps[4] = {hp4.x, hp4.y, hp4.z, hp4.w};
        float dhs[4] = {dh4.x, dh4.y, dh4.z, dh4.w};
        u16 fvs[4]   = {fv4.x, fv4.y, fv4.z, fv4.w};
#pragma unroll
        for (int j = 0; j < 4; ++j) {
            float g = gs[j], hp = hps[j], dh = dhs[j];
            float sg = 1.f / (1.f + expf(-g));
            float silu_g = g * sg;
            la[r][tc4 + j]  = f2bf(dh * hp * (sg * (1.f + g * (1.f - sg))) * l0);
            lb[r][tc4 + j]  = f2bf(dh * silu_g * l2);
            lc[r][tc4 + j]  = f2bf(bf2f(fvs[j]) * l1);
            ldt[r][tc4 + j] = f2bf(silu_g * hp);
        }
    }
    __syncthreads();
#pragma unroll
    for (int it = 0; it < 4; ++it) {
        int r = tr + it * 16;            // local f (output row)
        long obase = ((long)z * 512 + f0 + r) * 1024 + ci0 + tc4;
        ushort4 va, vb, vc, vd;
        va.x = la[tc4][r];  va.y = la[tc4+1][r];  va.z = la[tc4+2][r];  va.w = la[tc4+3][r];
        vb.x = lb[tc4][r];  vb.y = lb[tc4+1][r];  vb.z = lb[tc4+2][r];  vb.w = lb[tc4+3][r];
        vc.x = lc[tc4][r];  vc.y = lc[tc4+1][r];  vc.z = lc[tc4+2][r];  vc.w = lc[tc4+3][r];
        vd.x = ldt[tc4][r]; vd.y = ldt[tc4+1][r]; vd.z = ldt[tc4+2][r]; vd.w = ldt[tc4+3][r];
        *reinterpret_cast<ushort4*>(&ta[obase]) = va;
        *reinterpret_cast<ushort4*>(&tb[obase]) = vb;
        *reinterpret_cast<ushort4*>(&tc[obase]) = vc;
        *reinterpret_cast<ushort4*>(&td[obase]) = vd;
    }
}

// scan elementwise 2 + cvt: hq = bf16(silu(gq) * hq2), gq|hq2 in T12
__global__ void scan_ew2c(const float* __restrict__ T12, u16* __restrict__ hq)
{
    long idx = (long)blockIdx.x * 256 + threadIdx.x;   // 8*1024*512
    int f = (int)(idx & 511);
    long r = idx >> 9;
    long base12 = r * 1024;
    float g = T12[base12 + f];
    float h2 = T12[base12 + 512 + f];
    float v = g * (1.f / (1.f + expf(-g))) * h2;
    hq[idx] = f2bf(v);
}

// ---------------------------------------------------------------------------
// ttt rmsnorm + add attX -> bf16 x_b directly (fused, saves attX round trip)
// ---------------------------------------------------------------------------
__global__ __launch_bounds__(128) void ttt_norm_cvt(
    const float* __restrict__ ttt, const float* __restrict__ w,
    const float* __restrict__ attnX, u16* __restrict__ xb)
{
    int bid = blockIdx.x;
    int h = bid & 3;
    int row = bid >> 2;
    const float* x = &ttt[(long)row * 2048 + h * 512];
    __shared__ float red[128];
    float v[4];
    float ss = 0.f;
#pragma unroll
    for (int ii = 0; ii < 4; ++ii) {
        v[ii] = x[threadIdx.x + ii * 128];
        ss += v[ii] * v[ii];
    }
    red[threadIdx.x] = ss; __syncthreads();
    for (int s_ = 64; s_ > 0; s_ >>= 1) {
        if (threadIdx.x < s_) red[threadIdx.x] += red[threadIdx.x + s_];
        __syncthreads();
    }
    float sc = rsqrtf(red[0] / 512.f + 1e-6f);
    const float* a = &attnX[(long)row * 2048 + h * 512];
    u16* o = &xb[(long)row * 2048 + h * 512];
#pragma unroll
    for (int ii = 0; ii < 4; ++ii) {
        int i = threadIdx.x + ii * 128;
        o[i] = f2bf(a[i] + v[ii] * sc * w[i]);
    }
}

// ---------------------------------------------------------------------------
extern "C" void kernel_launch(void* const* d_in, const int* in_sizes, int n_in,
                              void* d_out, int out_size, void* d_ws, size_t ws_size,
                              hipStream_t stream)
{
    const float* hs        = (const float*)d_in[0];
    const float* Wqkv      = (const float*)d_in[1];
    const float* Wo        = (const float*)d_in[2];
    const float* q_norm_w  = (const float*)d_in[3];
    const float* k_norm_w  = (const float*)d_in[4];
    const float* w0        = (const float*)d_in[5];
    const float* w1        = (const float*)d_in[6];
    const float* w2        = (const float*)d_in[7];
    const float* lr_w      = (const float*)d_in[8];
    const float* lr_b      = (const float*)d_in[9];
    const float* qk_scale  = (const float*)d_in[10];
    const float* qk_offset = (const float*)d_in[11];
    const float* ttt_w     = (const float*)d_in[12];
    float* out = (float*)d_out;
    float* ws = (float*)d_ws;

    // ---- workspace (fp32 units), total 65,060,864 floats = 248.2 MiB -------
    const long F_QKV = 0;          // qkv fp32 (25,165,824); later:
    const long F_TTT = 0;          //   ttt fp32 (8,388,608)
    const long F_T1  = 8388608;    //   T12 fp32 (8,388,608); later x_b bf16
    const long F_T3  = 16777216;   //   T3 fp32 (4,194,304); later wo_b bf16
    const long F_TC  = 20971520;   //   ttc bf16 (4,194,304 elems = 2,097,152 fl)
    const long F_TD  = 23068672;   //   ttd bf16 (2,097,152 fl)
    const long F_AQ  = 25165824;   // hs_b -> aq bf16 + vt bf16 -> fq_b | fk_b
    const long F_AK  = 33554432;   // Wqkv_b -> ak bf16 -> fv_b | hq_b | fkt
    const long F_ATT = 41943040;   // attX fp32 (8,388,608)
    const long F_TTa = 50331648;   // transposed bf16 temp A (2,097,152 fl)
    const long F_TTb = 52428800;   // transposed bf16 temp B (2,097,152 fl)
    const long F_W0  = 54525952;   // weights fp32 (3 x 2,097,152)
    const long F_W1  = 56623104;
    const long F_W2  = 58720256;
    const long F_W02B= 60817408;   // packed w0|w2 bf16 (8,1024,512)
    const long F_W1B = 62914560;   // w1 bf16 snapshot
    const long F_W1T = 63963136;   // w1^T bf16
    const long F_LR  = 65011712;   // end 65,060,864

    u16* hs_b   = (u16*)(ws + F_AQ);
    u16* wqkv_b = (u16*)(ws + F_AK);
    u16* aq_b   = (u16*)(ws + F_AQ);
    u16* ak_b   = (u16*)(ws + F_AK);
    u16* vt_b   = (u16*)(ws + F_AQ + 4194304);
    u16* fq_b   = (u16*)(ws + F_AQ);
    u16* fk_b   = (u16*)(ws + F_AQ + 4194304);
    u16* fv_b   = (u16*)(ws + F_AK);
    u16* hq_b   = (u16*)(ws + F_AK + 4194304);
    u16* fkt_b  = (u16*)(ws + F_AK + 6291456);
    u16* tta    = (u16*)(ws + F_TTa);
    u16* ttb    = (u16*)(ws + F_TTb);
    u16* ttc    = (u16*)(ws + F_TC);
    u16* ttd    = (u16*)(ws + F_TD);
    u16* w02b_u = (u16*)(ws + F_W02B);
    u16* w1b_u  = (u16*)(ws + F_W1B);
    u16* w1t_u  = (u16*)(ws + F_W1T);
    u16* x_b    = (u16*)(ws + F_T1);   // after scan
    u16* wo_b   = (u16*)(ws + F_T3);   // after scan

    // 1. qkv = hs @ Wqkv^T  (bf16 MFMA)
    cvt_bf16<<<8192, 256, 0, stream>>>(hs, hs_b, 8388608);
    cvt_bf16<<<12288, 256, 0, stream>>>(Wqkv, wqkv_b, 12582912);
    gemm_mfma<<<dim3(48, 32, 1), 256, 0, stream>>>(
        hs_b, 2048, 0, 0, wqkv_b, 2048, 0, 0, ws + F_QKV, 6144, 0, 0, 2048, 0);
    // 2. lr
    lr_kernel<<<4096, 256, 0, stream>>>(hs, lr_w, lr_b, ws + F_LR);
    // 3. rmsnorm + rope -> bf16
    rmsnorm_rope<<<4096, 256, 0, stream>>>(ws + F_QKV, 0,    q_norm_w, aq_b);
    rmsnorm_rope<<<4096, 256, 0, stream>>>(ws + F_QKV, 2048, k_norm_w, ak_b);
    // 3b. V transpose for attention
    vt_prep<<<dim3(32, 2, 32), 256, 0, stream>>>(ws + F_QKV, vt_b);
    // 4. attention (bf16 MFMA)
    attn_mfma<<<dim3(32, 16, 2), 256, 0, stream>>>(aq_b, ak_b, vt_b, ws + F_ATT);
    // 5. fq/fk/fv bf16 (one launch, 3 modes)
    fqkv_kernel<<<dim3(16384, 3), 128, 0, stream>>>(
        ws + F_QKV, qk_scale, qk_offset, fq_b, fk_b, fv_b);
    // 6. fast-weight init (fp32 masters)
    winit<<<8192, 256, 0, stream>>>(w0, w1, w2, ws + F_W0, ws + F_W1, ws + F_W2);

    for (int c0 = 0; c0 < 2; ++c0) {
        const long cOff = (long)c0 * 2097152;           // chunk offset in bf16 elems
        // packed bf16 snapshots: w02 = [w0; w2] rows, plus w1^T
        cvt_pack<<<2048, 256, 0, stream>>>(ws + F_W0, w02b_u, 0);
        cvt_pack<<<2048, 256, 0, stream>>>(ws + F_W2, w02b_u, 1);
        transpose_cvt<float><<<dim3(8, 8, 8), 256, 0, stream>>>(
            ws + F_W1, 512, 1048576, 262144, w1t_u, 512, 1048576, 262144);
        // fk^T for the updates
        transpose_cvt<u16><<<dim3(8, 16, 8), 256, 0, stream>>>(
            fk_b + cOff, 2048, 4194304, 512, fkt_b, 1024, 2097152, 524288);
        // gate|hpre fused (N=1024) + dh
        gemm_mfma<<<dim3(8, 8, 8), 256, 0, stream>>>(
            fk_b + cOff, 2048, 4194304, 512, w02b_u, 512, 2097152, 524288,
            ws + F_T1, 1024, 4194304, 1048576, 512, 0);
        gemm_mfma<<<dim3(4, 8, 8), 256, 0, stream>>>(
            fv_b + cOff, 2048, 4194304, 512, w1t_u, 512, 1048576, 262144,
            ws + F_T3, 512, 2097152, 524288, 512, 0);
        // elementwise + fused transpose -> 4 bf16 operands
        scan_ew1t<<<dim3(8, 16, 8), 256, 0, stream>>>(
            ws + F_T1, ws + F_T3, fv_b, ws + F_LR, c0, tta, ttb, ttc, ttd);
        // weight updates (64-tile GEMMs, grid 512)
        gemm_mfma64<<<dim3(8, 8, 8), 256, 0, stream>>>(
            tta, 1024, 2097152, 524288, fkt_b, 1024, 2097152, 524288,
            ws + F_W0, 512, 1048576, 262144, 1024, 1);
        gemm_mfma64<<<dim3(8, 8, 8), 256, 0, stream>>>(
            ttb, 1024, 2097152, 524288, fkt_b, 1024, 2097152, 524288,
            ws + F_W2, 512, 1048576, 262144, 1024, 1);
        gemm_mfma64<<<dim3(8, 8, 8), 256, 0, stream>>>(
            ttc, 1024, 2097152, 524288, ttd, 1024, 2097152, 524288,
            ws + F_W1, 512, 1048576, 262144, 1024, 1);
        // query pass with updated weights (gq|hq2 fused)
        cvt_pack<<<2048, 256, 0, stream>>>(ws + F_W0, w02b_u, 0);
        cvt_pack<<<2048, 256, 0, stream>>>(ws + F_W2, w02b_u, 1);
        cvt_bf16<<<2048, 256, 0, stream>>>(ws + F_W1, w1b_u, 2097152);
        gemm_mfma<<<dim3(8, 8, 8), 256, 0, stream>>>(
            fq_b + cOff, 2048, 4194304, 512, w02b_u, 512, 2097152, 524288,
            ws + F_T1, 1024, 4194304, 1048576, 512, 0);
        scan_ew2c<<<16384, 256, 0, stream>>>(ws + F_T1, hq_b);
        // oi = hq @ w1^T -> ttt (strided (b,s,NH,fd))
        gemm_mfma<<<dim3(4, 8, 8), 256, 0, stream>>>(
            hq_b, 512, 2097152, 524288, w1b_u, 512, 1048576, 262144,
            ws + F_TTT + cOff, 2048, 4194304, 512, 512, 0);
    }

    // 8. ttt rmsnorm + add attX -> x_b bf16 (fused)
    ttt_norm_cvt<<<16384, 128, 0, stream>>>(ws + F_TTT, ttt_w, ws + F_ATT, x_b);
    // 9. out = X @ Wo^T  (bf16 MFMA)
    cvt_bf16<<<4096, 256, 0, stream>>>(Wo, wo_b, 4194304);
    gemm_mfma<<<dim3(16, 32, 1), 256, 0, stream>>>(
        x_b, 2048, 0, 0, wo_b, 2048, 0, 0, out, 2048, 0, 0, 2048, 0);
}